// Round 6
// baseline (281.425 us; speedup 1.0000x reference)
//
#include <hip/hip_runtime.h>
#include <hip/hip_bf16.h>
#include <math.h>

// ---------------------------------------------------------------------------
// MMD-VAE fused pipeline for MI355X (gfx950)
// B=8 S=512 D=1024 DI=4096 DL=64, Nrows = B*S = 4096
// Outputs: recon [4096,1024] f32, latent [4096,64] f32, reg_loss scalar f32
// ---------------------------------------------------------------------------

typedef __attribute__((ext_vector_type(8))) short short8;    // 8 bf16 = 4 VGPR
typedef __attribute__((ext_vector_type(4))) float float4a;   // MFMA accum
typedef __attribute__((ext_vector_type(4))) unsigned short us4;

__device__ inline ushort bf16r(float x) {
    union { float f; unsigned u; } c; c.f = x;
    unsigned r = (c.u + 0x7fffu + ((c.u >> 16) & 1u)) >> 16;
    return (ushort)r;
}

// async global->LDS, 16B per lane, LDS dst = wave-uniform base + lane*16
__device__ inline void gld_lds16(const void* g, void* l) {
    __builtin_amdgcn_global_load_lds(
        (const __attribute__((address_space(1))) void*)g,
        (__attribute__((address_space(3))) void*)l, 16, 0, 0);
}

template <int N> __device__ inline void wait_vmcnt() {
    if constexpr (N == 0) asm volatile("s_waitcnt vmcnt(0)" ::: "memory");
    else if constexpr (N == 4) asm volatile("s_waitcnt vmcnt(4)" ::: "memory");
    else if constexpr (N == 6) asm volatile("s_waitcnt vmcnt(6)" ::: "memory");
}

template <int N> __device__ inline void wait_lgkmcnt() {
    if constexpr (N == 0) asm volatile("s_waitcnt lgkmcnt(0)" ::: "memory");
    else if constexpr (N == 2) asm volatile("s_waitcnt lgkmcnt(2)" ::: "memory");
    else if constexpr (N == 4) asm volatile("s_waitcnt lgkmcnt(4)" ::: "memory");
    else if constexpr (N == 6) asm volatile("s_waitcnt lgkmcnt(6)" ::: "memory");
    else if constexpr (N == 8) asm volatile("s_waitcnt lgkmcnt(8)" ::: "memory");
}

// runtime-form counted wait: N is constant-folded after full unroll
__device__ inline void wait_lgkm_dyn(int n) {
    if (n == 0) wait_lgkmcnt<0>();
    else if (n == 2) wait_lgkmcnt<2>();
    else if (n == 4) wait_lgkmcnt<4>();
    else if (n == 6) wait_lgkmcnt<6>();
    else wait_lgkmcnt<8>();
}

// tanh-form gelu via sigmoid identity: 0.5v(1+tanh(z)) = v*sigmoid(2z).
// 2z = 1.5957691*v + 0.07135482*v^3.  |err| <~1e-3 (<< bf16 rounding here).
__device__ inline float fast_gelu(float v) {
    float v2 = v * v;
    float u = v * __builtin_fmaf(0.07135481627f, v2, 1.5957691216f);
    u = fminf(u, 30.0f);                       // overflow guard
    float e = __expf(u);
    return v * e * __builtin_amdgcn_rcpf(e + 1.0f);
}

// ---------------- fused pre-pass: conversions + transposes + zeroing -------
__global__ __launch_bounds__(256) void k_pre(
        const float* __restrict__ hidden, ushort* __restrict__ A1bf,
        const float* __restrict__ tsamp, ushort* __restrict__ Tbf,
        float* __restrict__ sq_t, float* __restrict__ acc,
        const float* __restrict__ i0, ushort* __restrict__ o0,
        const float* __restrict__ i1, ushort* __restrict__ o1,
        const float* __restrict__ i2, ushort* __restrict__ o2,
        const float* __restrict__ i3, ushort* __restrict__ o3) {
    int b = blockIdx.x, tid = threadIdx.x;
    if (b == 0 && tid < 24) acc[tid] = 0.0f;   // 3 accumulators, 1 per line
    if (b < 4096) {
        int i = b * 1024 + tid * 4;
        float4 v = *(const float4*)(hidden + i);
        us4 o = {bf16r(v.x), bf16r(v.y), bf16r(v.z), bf16r(v.w)};
        *(us4*)(A1bf + i) = o;
        return;
    }
    if (b < 4352) {
        int i = (b - 4096) * 1024 + tid * 4;
        float4 v = *(const float4*)(tsamp + i);
        us4 o = {bf16r(v.x), bf16r(v.y), bf16r(v.z), bf16r(v.w)};
        *(us4*)(Tbf + i) = o;
        float s = v.x * v.x + v.y * v.y + v.z * v.z + v.w * v.w;
#pragma unroll
        for (int off = 8; off; off >>= 1) s += __shfl_xor(s, off);
        if ((tid & 15) == 0) sq_t[i >> 6] = s;
        return;
    }
    // transpose section
    __shared__ float t[32][33];
    const float* in; ushort* out; int R, C, lb;
    if (b < 8448)      { in = i0; out = o0; R = 1024; C = 4096; lb = b - 4352; }
    else if (b < 8704) { in = i1; out = o1; R = 4096; C = 64;   lb = b - 8448; }
    else if (b < 8960) { in = i2; out = o2; R = 64;   C = 4096; lb = b - 8704; }
    else               { in = i3; out = o3; R = 4096; C = 1024; lb = b - 8960; }
    int bx = (lb % (C / 32)) * 32;
    int by = (lb / (C / 32)) * 32;
    int tx = tid & 31, ty = tid >> 5;   // ty 0..7
#pragma unroll
    for (int i = 0; i < 32; i += 8)
        t[ty + i][tx] = in[(size_t)(by + ty + i) * C + (bx + tx)];
    __syncthreads();
#pragma unroll
    for (int i = 0; i < 32; i += 8)
        out[(size_t)(bx + ty + i) * R + (by + tx)] = bf16r(t[tx][ty + i]);
}

// ---------------- MFMA GEMM (2-barrier structure, kept for GEMM2/GEMM3) ----
// BM=128, BK=64, LDK=64, XOR swizzle k8^=row&7 on staging + read (0 bank
// conflicts).  BN=64: 4x1 waves of 32x64.
// EPI 0: +bias, gelu -> bf16 out.   EPI 1: +bias -> f32 out.
// EPI 2: raw fp32 partial (split-K): z==0 -> Out, z>0 -> Out2 if given.
template <int BN, int EPI, bool SWZ>
__global__ __launch_bounds__(256) void k_gemm(
        const ushort* __restrict__ A, const ushort* __restrict__ Bt,
        const float* __restrict__ bias, void* __restrict__ Out,
        float* __restrict__ Out2, int M, int N, int K, int KC) {
    constexpr int BM = 128, BK = 64;
    constexpr int WAVES_N = BN / 64;
    constexpr int WAVES_M = 4 / WAVES_N;
    constexpr int WM = BM / WAVES_M;
    constexpr int MT = WM / 16;
    constexpr int NT = 4;
    constexpr int CA = BM / 32, CB = BN / 32;

    __shared__ ushort sA[BM * 64];
    __shared__ ushort sB[BN * 64];

    const int tid  = threadIdx.x;
    const int wave = tid >> 6, lane = tid & 63;
    const int wm = wave / WAVES_N, wn = wave % WAVES_N;
    int bx = blockIdx.x, by = blockIdx.y;
    if constexpr (SWZ) {
        int lin = blockIdx.x + gridDim.x * blockIdx.y;
        by = lin % gridDim.y;          // m-tile fast => same XCD per A-row
        bx = lin / gridDim.y;
    }
    const int m0 = by * BM, n0 = bx * BN;
    const int lrow = lane & 15, lq = lane >> 4;
    const int srow8 = lane >> 3;
    const int sk8   = lane & 7;
    const int kbeg = blockIdx.z * KC;

    const ushort* pA[CA]; unsigned lA[CA];
#pragma unroll
    for (int j = 0; j < CA; ++j) {
        int c = wave * CA + j;
        int r = c * 8 + srow8;
        pA[j] = &A[(size_t)(m0 + r) * K + kbeg + ((sk8 ^ (r & 7)) * 8)];
        lA[j] = c * 512;
    }
    const ushort* pB[CB]; unsigned lB[CB];
#pragma unroll
    for (int j = 0; j < CB; ++j) {
        int c = wave * CB + j;
        int r = c * 8 + srow8;
        pB[j] = &Bt[(size_t)(n0 + r) * K + kbeg + ((sk8 ^ (r & 7)) * 8)];
        lB[j] = c * 512;
    }
    unsigned aoff[2][MT], boff[2][NT];
#pragma unroll
    for (int h = 0; h < 2; ++h) {
#pragma unroll
        for (int mt = 0; mt < MT; ++mt) {
            int r = wm * WM + mt * 16 + lrow;
            aoff[h][mt] = r * 64 + (((h * 4 + lq) ^ (r & 7)) * 8);
        }
#pragma unroll
        for (int nt = 0; nt < NT; ++nt) {
            int r = wn * 64 + nt * 16 + lrow;
            boff[h][nt] = r * 64 + (((h * 4 + lq) ^ (r & 7)) * 8);
        }
    }

    float4a acc[MT][NT];
#pragma unroll
    for (int mt = 0; mt < MT; ++mt)
#pragma unroll
        for (int nt = 0; nt < NT; ++nt)
            acc[mt][nt] = (float4a){0.f, 0.f, 0.f, 0.f};

    for (int k0 = 0; k0 < KC; k0 += BK) {
#pragma unroll
        for (int j = 0; j < CA; ++j) {
            gld_lds16(pA[j], &sA[lA[j]]);
            pA[j] += BK;
        }
#pragma unroll
        for (int j = 0; j < CB; ++j) {
            gld_lds16(pB[j], &sB[lB[j]]);
            pB[j] += BK;
        }
        __syncthreads();
#pragma unroll
        for (int h = 0; h < 2; ++h) {
            short8 af[MT], bfr[NT];
#pragma unroll
            for (int mt = 0; mt < MT; ++mt)
                af[mt] = *(short8*)(&sA[aoff[h][mt]]);
#pragma unroll
            for (int nt = 0; nt < NT; ++nt)
                bfr[nt] = *(short8*)(&sB[boff[h][nt]]);
#pragma unroll
            for (int mt = 0; mt < MT; ++mt)
#pragma unroll
                for (int nt = 0; nt < NT; ++nt)
                    acc[mt][nt] = __builtin_amdgcn_mfma_f32_16x16x32_bf16(
                        af[mt], bfr[nt], acc[mt][nt], 0, 0, 0);
        }
        __syncthreads();
    }

    float* dstp = nullptr;
    if constexpr (EPI == 2) {
        if (Out2 && blockIdx.z) dstp = Out2;
        else dstp = (float*)Out + (size_t)blockIdx.z * M * N;
    }
#pragma unroll
    for (int mt = 0; mt < MT; ++mt)
#pragma unroll
        for (int nt = 0; nt < NT; ++nt) {
            int col = n0 + wn * 64 + nt * 16 + lrow;
            float bv = 0.f;
            if constexpr (EPI != 2) bv = bias[col];
#pragma unroll
            for (int r = 0; r < 4; ++r) {
                int row = m0 + wm * WM + mt * 16 + lq * 4 + r;
                float v = acc[mt][nt][r] + bv;
                if constexpr (EPI == 0) {
                    ((ushort*)Out)[(size_t)row * N + col] = bf16r(fast_gelu(v));
                } else if constexpr (EPI == 1) {
                    ((float*)Out)[(size_t)row * N + col] = v;
                } else {
                    dstp[(size_t)row * N + col] = v;
                }
            }
        }
}

// ---------------- 256-row pipelined MFMA GEMM (step-pipelined) -------------
// BM=256, BK=64, 512 threads = 8 waves, double-buffered LDS, XOR-slot
// swizzle (0-conflict).  Register-level software pipeline at step
// granularity: a step = 2 m-rows x NT = 8 MFMAs; NS = MT steps/tile.  Each
// iteration issues ONLY step s+2's reads (2 ds_read, +NT at a k-half
// start), then counted lgkmcnt(N) with N = reads outstanding for steps
// s+1,s+2 (DS ops complete in order), then 8 MFMAs.  LDS pipe gets fresh
// work every step while MFMAs run -> pipes overlap.  Boundary: stage t+1
// into dead buffer at tile start, one vmcnt(0)+s_barrier per tile.
// R5 post-mortem: NS=4 (BN=128) hits the LDS-pipe roofline (~20.5us for 32
// CU-tiles); NS=8 (BN=256) REGRESSED 1.8x (72.7us) -- 8 wait-points/tile
// with 2-read batches starve the LDS queue.  USE ONLY BN=128 (NS=4).
// BN=128: waves 4Mx2N, per-wave C 64x64, NS=4, waits {8,8,2,0}.
// XCD swizzle (bijective, chunked): XCD x gets 32 blocks forming a CX x CY
// sub-rectangle (z slowest).
// EPI 0: +bias, gelu -> bf16.  EPI 2: raw f32 split-K partial.
template <int BN, int EPI, int CX, int CY>
__global__ __launch_bounds__(512, 2) void k_gemm256(
        const ushort* __restrict__ A, const ushort* __restrict__ Bt,
        const float* __restrict__ bias, void* __restrict__ Out,
        float* __restrict__ Out2, int M, int N, int K, int KC) {
    constexpr int BM = 256, BK = 64;
    constexpr int AI = 4;                    // A stage issues/tile (8KB each)
    constexpr int BI = BN / 64;              // B stage issues/tile
    constexpr int WAVES_N = BN / 64;         // 2
    constexpr int WAVES_M = 8 / WAVES_N;     // 4
    constexpr int WM = BM / WAVES_M;         // 64
    constexpr int MT = WM / 16;              // 4
    constexpr int NT = 4;
    constexpr int NS = MT;                   // pipeline steps per tile
    constexpr int NS2 = MT / 2;              // steps per k-half

    __shared__ ushort sA[2][BM * 64];
    __shared__ ushort sB[2][BN * 64];

    const int tid = threadIdx.x;
    const int wave = tid >> 6, lane = tid & 63;
    const int wm = wave / WAVES_N, wn = wave % WAVES_N;

    // ---- chunked XCD swizzle (bijective: nwg % 8 == 0 by construction) ----
    const int gx = gridDim.x, gy = gridDim.y;
    const int lin = blockIdx.x + gx * (blockIdx.y + gy * blockIdx.z);
    const int nwg = gx * gy * gridDim.z;
    const int cpx = nwg >> 3;
    const int swz = (lin & 7) * cpx + (lin >> 3);
    const int nz  = gx * gy;                 // blocks per z-slice
    const int zz  = swz / nz;
    const int rr  = swz % nz;
    const int chunk = rr / (CX * CY);
    const int lcl   = rr % (CX * CY);
    const int ncx   = gx / CX;
    const int bx = (chunk % ncx) * CX + (lcl % CX);
    const int by = (chunk / ncx) * CY + (lcl / CX);

    const int m0 = by * BM, n0 = bx * BN;
    const int lrow = lane & 15, lq = lane >> 4;
    const int kbeg = zz * KC;
    const int nT = KC / BK;

    // staging: block-wide issue j covers rows 64j..64j+63; thread t = row
    // (t>>3), slot (t&7); global k8 pre-swizzled so linear LDS dest works.
    const int crow = tid >> 3;                    // 0..63
    const int ck8  = (tid & 7) ^ (crow & 7);
    const ushort* pAbase = A  + (size_t)(m0 + crow) * K + kbeg + ck8 * 8;
    const ushort* pBbase = Bt + (size_t)(n0 + crow) * K + kbeg + ck8 * 8;

    // fragment read bases: row&7 == lrow&7 (tiles are 16-aligned), so the
    // swizzled slot depends only on the k-half h -> 2 constants.
    const int a0  = (wm * WM + lrow) * 64;
    const int b0  = (wn * 64 + lrow) * 64;
    const int sw0 = ((lq) ^ (lrow & 7)) * 8;
    const int sw1 = ((4 + lq) ^ (lrow & 7)) * 8;

    float4a acc[MT][NT];
#pragma unroll
    for (int mt = 0; mt < MT; ++mt)
#pragma unroll
        for (int nt = 0; nt < NT; ++nt)
            acc[mt][nt] = (float4a){0.f, 0.f, 0.f, 0.f};

    // ---------------- prologue: tile 0 -> buf 0 ----------------
#pragma unroll
    for (int j = 0; j < AI; ++j)
        gld_lds16(pAbase + (size_t)j * 64 * K, &sA[0][j * 4096 + wave * 512]);
#pragma unroll
    for (int j = 0; j < BI; ++j)
        gld_lds16(pBbase + (size_t)j * 64 * K, &sB[0][j * 4096 + wave * 512]);
    wait_vmcnt<0>();
    __builtin_amdgcn_s_barrier();
    __builtin_amdgcn_sched_barrier(0);

    for (int t = 0; t < nT; ++t) {
        const int d = t & 1;
        const bool pf1 = (t + 1 < nT);
        const size_t koff1 = (size_t)(t + 1) * BK;

        short8 af[NS][2], bfr[2][NT];

        // S0: bfr[h=0] + af[0] (2+NT reads)
#pragma unroll
        for (int nt = 0; nt < NT; ++nt)
            bfr[0][nt] = *(const short8*)(&sB[d][b0 + nt * 1024 + sw0]);
        af[0][0] = *(const short8*)(&sA[d][a0 + 0 * 1024 + sw0]);
        af[0][1] = *(const short8*)(&sA[d][a0 + 1 * 1024 + sw0]);
        __builtin_amdgcn_sched_barrier(0);
        // S1: af[1] (2 reads)
        af[1][0] = *(const short8*)(&sA[d][a0 + 2 * 1024 + sw0]);
        af[1][1] = *(const short8*)(&sA[d][a0 + 3 * 1024 + sw0]);
        __builtin_amdgcn_sched_barrier(0);
        if (pf1) {                            // stage t+1 into dead buffer
#pragma unroll
            for (int j = 0; j < AI; ++j)
                gld_lds16(pAbase + (size_t)j * 64 * K + koff1,
                          &sA[d ^ 1][j * 4096 + wave * 512]);
#pragma unroll
            for (int j = 0; j < BI; ++j)
                gld_lds16(pBbase + (size_t)j * 64 * K + koff1,
                          &sB[d ^ 1][j * 4096 + wave * 512]);
        }
        __builtin_amdgcn_sched_barrier(0);

#pragma unroll
        for (int s = 0; s < NS; ++s) {
            const int s2 = s + 2;
            if (s2 < NS) {                    // issue step s+2's reads
                const int h2 = s2 / NS2;
                const int mb2 = (s2 % NS2) * 2;
                const int swh2 = h2 ? sw1 : sw0;
                if ((s2 % NS2) == 0) {        // new k-half: B frags too
#pragma unroll
                    for (int nt = 0; nt < NT; ++nt)
                        bfr[h2][nt] =
                            *(const short8*)(&sB[d][b0 + nt * 1024 + swh2]);
                }
                af[s2][0] = *(const short8*)(&sA[d][a0 + (mb2 + 0) * 1024 + swh2]);
                af[s2][1] = *(const short8*)(&sA[d][a0 + (mb2 + 1) * 1024 + swh2]);
                __builtin_amdgcn_sched_barrier(0);
            }
            // counted wait: steps s+1, s+2 may remain outstanding
            int Ns = 0;
            if (s + 1 < NS) Ns += (((s + 1) % NS2) == 0) ? (2 + NT) : 2;
            if (s + 2 < NS) Ns += (((s + 2) % NS2) == 0) ? (2 + NT) : 2;
            wait_lgkm_dyn(Ns);
            __builtin_amdgcn_sched_barrier(0);
            const int h = s / NS2, mb = (s % NS2) * 2;
            __builtin_amdgcn_s_setprio(1);
#pragma unroll
            for (int i = 0; i < 2; ++i)
#pragma unroll
                for (int nt = 0; nt < NT; ++nt)
                    acc[mb + i][nt] = __builtin_amdgcn_mfma_f32_16x16x32_bf16(
                        af[s][i], bfr[h][nt], acc[mb + i][nt], 0, 0, 0);
            __builtin_amdgcn_s_setprio(0);
        }
        if (pf1) {                            // boundary: the only barrier
            wait_vmcnt<0>();
            __builtin_amdgcn_s_barrier();
            __builtin_amdgcn_sched_barrier(0);
        }
    }

    // ---------------- epilogue ----------------
    float* dstp = nullptr;
    if constexpr (EPI == 2) {
        if (Out2 && zz) dstp = Out2;
        else dstp = (float*)Out + (size_t)zz * M * N;
    }
#pragma unroll
    for (int mt = 0; mt < MT; ++mt)
#pragma unroll
        for (int nt = 0; nt < NT; ++nt) {
            const int col = n0 + wn * 64 + nt * 16 + lrow;
            float bv = 0.f;
            if constexpr (EPI == 0) bv = bias[col];
#pragma unroll
            for (int r = 0; r < 4; ++r) {
                const int row = m0 + wm * WM + mt * 16 + lq * 4 + r;
                float v = acc[mt][nt][r] + bv;
                if constexpr (EPI == 0)
                    ((ushort*)Out)[(size_t)row * N + col] = bf16r(fast_gelu(v));
                else
                    dstp[(size_t)row * N + col] = v;
            }
        }
}

// ---------------- fused MMD grams (separate-line accumulators) -------------
// blocks 0..527: tt upper-triangle tiles; 528..1055: ll; 1056..2079: tl full.
// Off-diagonal symmetric tiles weighted 2x; diagonal tiles exact (incl i==j).
__global__ __launch_bounds__(256) void k_gram_all(
        const ushort* __restrict__ Tbf, const ushort* __restrict__ Lbf,
        const float* __restrict__ sq_t, const float* __restrict__ sq_l,
        float* __restrict__ accum) {
    __shared__ ushort sX[128 * 64];
    __shared__ ushort sY[128 * 64];
    __shared__ float red[4];

    int id = blockIdx.x;
    int pair, tbx, tby; float w;
    if (id < 1056) {
        pair = (id < 528) ? 0 : 1;
        int t = (pair == 0) ? id : id - 528;
        int r = (int)((sqrtf(8.0f * t + 1.0f) - 1.0f) * 0.5f);
        while ((r + 1) * (r + 2) / 2 <= t) ++r;
        while (r * (r + 1) / 2 > t) --r;
        tby = r; tbx = t - r * (r + 1) / 2;
        w = (tbx == tby) ? 1.0f : 2.0f;
    } else {
        pair = 2; int t = id - 1056;
        tbx = t & 31; tby = t >> 5; w = 1.0f;
    }
    const ushort* Xb = (pair == 1) ? Lbf : Tbf;
    const ushort* Yb = (pair == 0) ? Tbf : Lbf;
    const float* sqX = (pair == 1) ? sq_l : sq_t;
    const float* sqY = (pair == 0) ? sq_t : sq_l;

    const int tid  = threadIdx.x;
    const int wave = tid >> 6, lane = tid & 63;
    const int wm = wave >> 1, wn = wave & 1;
    const int bx = tbx * 128, by = tby * 128;
    const int lrow = lane & 15, lq = lane >> 4;
    const int srow8 = lane >> 3, sk8 = lane & 7;

#pragma unroll
    for (int j = 0; j < 4; ++j) {
        int c = wave * 4 + j;
        int r = c * 8 + srow8;
        int kc = (sk8 ^ (r & 7)) * 8;
        gld_lds16(&Xb[(size_t)(bx + r) * 64 + kc], &sX[c * 512]);
        gld_lds16(&Yb[(size_t)(by + r) * 64 + kc], &sY[c * 512]);
    }

    unsigned xoff[2][4], yoff[2][4];
#pragma unroll
    for (int h = 0; h < 2; ++h)
#pragma unroll
        for (int i = 0; i < 4; ++i) {
            int rx = wm * 64 + i * 16 + lrow;
            int ry = wn * 64 + i * 16 + lrow;
            xoff[h][i] = rx * 64 + (((h * 4 + lq) ^ (rx & 7)) * 8);
            yoff[h][i] = ry * 64 + (((h * 4 + lq) ^ (ry & 7)) * 8);
        }
    __syncthreads();

    float4a acc[4][4];
#pragma unroll
    for (int mt = 0; mt < 4; ++mt)
#pragma unroll
        for (int nt = 0; nt < 4; ++nt)
            acc[mt][nt] = (float4a){0.f, 0.f, 0.f, 0.f};

#pragma unroll
    for (int h = 0; h < 2; ++h) {
        short8 xf[4], yf[4];
#pragma unroll
        for (int mt = 0; mt < 4; ++mt)
            xf[mt] = *(short8*)(&sX[xoff[h][mt]]);
#pragma unroll
        for (int nt = 0; nt < 4; ++nt)
            yf[nt] = *(short8*)(&sY[yoff[h][nt]]);
#pragma unroll
        for (int mt = 0; mt < 4; ++mt)
#pragma unroll
            for (int nt = 0; nt < 4; ++nt)
                acc[mt][nt] = __builtin_amdgcn_mfma_f32_16x16x32_bf16(
                    xf[mt], yf[nt], acc[mt][nt], 0, 0, 0);
    }

    float sy[4];
#pragma unroll
    for (int nt = 0; nt < 4; ++nt)
        sy[nt] = sqY[by + wn * 64 + nt * 16 + lrow];
    float s = 0.f;
#pragma unroll
    for (int mt = 0; mt < 4; ++mt)
#pragma unroll
        for (int r = 0; r < 4; ++r) {
            float sx = sqX[bx + wm * 64 + mt * 16 + lq * 4 + r];
#pragma unroll
            for (int nt = 0; nt < 4; ++nt)
                s += __expf((2.0f * acc[mt][nt][r] - sx - sy[nt]) * (1.0f / 4096.0f));
        }
    s *= w;
#pragma unroll
    for (int off = 32; off; off >>= 1) s += __shfl_xor(s, off);
    if ((tid & 63) == 0) red[tid >> 6] = s;
    __syncthreads();
    if (tid == 0) atomicAdd(accum + pair * 8, red[0] + red[1] + red[2] + red[3]);
}

// ---------------- LayerNorm over 64, split-K reduce, + latent sqnorm -------
__global__ __launch_bounds__(256) void k_ln64_red(
        const float* __restrict__ part, int npart,
        const float* __restrict__ bias, const float* __restrict__ g,
        const float* __restrict__ b, float* __restrict__ outf,
        ushort* __restrict__ outb, float* __restrict__ sq_l) {
    int wave = threadIdx.x >> 6, lane = threadIdx.x & 63;
    int row = blockIdx.x * 4 + wave;
    float x = bias[lane];
    for (int s = 0; s < npart; ++s)
        x += part[(size_t)s * 4096 * 64 + row * 64 + lane];
    float s = x;
#pragma unroll
    for (int off = 32; off; off >>= 1) s += __shfl_xor(s, off);
    float mu = s * (1.0f / 64.0f);
    float d = x - mu;
    float v = d * d;
#pragma unroll
    for (int off = 32; off; off >>= 1) v += __shfl_xor(v, off);
    float rs = rsqrtf(v * (1.0f / 64.0f) + 1e-9f);
    float y = d * rs * g[lane] + b[lane];
    outf[row * 64 + lane] = y;
    outb[row * 64 + lane] = bf16r(y);
    float q = y * y;
#pragma unroll
    for (int off = 32; off; off >>= 1) q += __shfl_xor(q, off);
    if (lane == 0) sq_l[row] = q;
}

// ---------------- LayerNorm over 1024 with 2-partial reduce ----------------
// p1 may alias out (read-before-write within the same block/row).
__global__ __launch_bounds__(256) void k_ln1024_red(
        const float* __restrict__ p0, const float* __restrict__ p1,
        const float* __restrict__ bias, const float* __restrict__ g,
        const float* __restrict__ b, float* __restrict__ out) {
    __shared__ float red[4];
    int row = blockIdx.x, tid = threadIdx.x;
    const float4 v0 = *(const float4*)(p0 + (size_t)row * 1024 + tid * 4);
    const float4 v1 = *(const float4*)(p1 + (size_t)row * 1024 + tid * 4);
    const float4 bb = *(const float4*)(bias + tid * 4);
    float4 v;
    v.x = v0.x + v1.x + bb.x;
    v.y = v0.y + v1.y + bb.y;
    v.z = v0.z + v1.z + bb.z;
    v.w = v0.w + v1.w + bb.w;
    float s = v.x + v.y + v.z + v.w;
#pragma unroll
    for (int off = 32; off; off >>= 1) s += __shfl_xor(s, off);
    if ((tid & 63) == 0) red[tid >> 6] = s;
    __syncthreads();
    float mu = (red[0] + red[1] + red[2] + red[3]) * (1.0f / 1024.0f);
    float dx = v.x - mu, dy = v.y - mu, dz = v.z - mu, dw = v.w - mu;
    float q = dx * dx + dy * dy + dz * dz + dw * dw;
#pragma unroll
    for (int off = 32; off; off >>= 1) q += __shfl_xor(q, off);
    __syncthreads();
    if ((tid & 63) == 0) red[tid >> 6] = q;
    __syncthreads();
    float rs = rsqrtf((red[0] + red[1] + red[2] + red[3]) * (1.0f / 1024.0f) + 1e-9f);
    const float4 gv = *(const float4*)(g + tid * 4);
    const float4 bv = *(const float4*)(b + tid * 4);
    float4 o;
    o.x = dx * rs * gv.x + bv.x;
    o.y = dy * rs * gv.y + bv.y;
    o.z = dz * rs * gv.z + bv.z;
    o.w = dw * rs * gv.w + bv.w;
    *(float4*)(out + (size_t)row * 1024 + tid * 4) = o;
}

__global__ void k_finalize(const float* __restrict__ accum, float* __restrict__ out) {
    // km_i = accum_i / 4096^2 ; reg = (km0 + km1 - 2*km2) / B * S = mmd * 64
    out[0] = (accum[0] + accum[8] - 2.0f * accum[16]) * (64.0f / (4096.0f * 4096.0f));
}

// ---------------------------------------------------------------------------
extern "C" void kernel_launch(void* const* d_in, const int* in_sizes, int n_in,
                              void* d_out, int out_size, void* d_ws, size_t ws_size,
                              hipStream_t stream) {
    const float* hidden   = (const float*)d_in[0];
    const float* tsamp    = (const float*)d_in[1];
    const float* enc_w1   = (const float*)d_in[2];
    const float* enc_b1   = (const float*)d_in[3];
    const float* enc_w2   = (const float*)d_in[4];
    const float* enc_b2   = (const float*)d_in[5];
    const float* enc_ln_g = (const float*)d_in[6];
    const float* enc_ln_b = (const float*)d_in[7];
    const float* dec_w1   = (const float*)d_in[8];
    const float* dec_b1   = (const float*)d_in[9];
    const float* dec_w2   = (const float*)d_in[10];
    const float* dec_b2   = (const float*)d_in[11];
    const float* dec_ln_g = (const float*)d_in[12];
    const float* dec_ln_b = (const float*)d_in[13];

    float* out      = (float*)d_out;
    float* recon    = out;                 // 4096*1024
    float* latent_f = out + 4194304;       // 4096*64
    float* reg      = out + 4456448;       // scalar

    char* ws = (char*)d_ws;
    const size_t MB = 1024 * 1024;
    ushort* A1bf = (ushort*)(ws + 0);                 // 8MB  hidden bf16 (dead after GEMM1)
    ushort* W1t  = (ushort*)(ws + 8 * MB);            // 8MB  (dead after GEMM1)
    float*  part = (float*)(ws + 0);                  // 16MB GEMM2 split-K partials [16][4096,64]
    float*  h4p0 = (float*)(ws + 0);                  // 16MB GEMM4 partial z=0 (z=1 -> recon buf)
    ushort* H1bf = (ushort*)(ws + 16 * MB);           // 32MB enc hidden, later dec hidden
    ushort* W4t  = (ushort*)(ws + 48 * MB);           // 8MB  [1024,4096]
    ushort* W2t  = (ushort*)(ws + 56 * MB);           // 512K [64,4096]
    ushort* W3t  = (ushort*)(ws + 56 * MB + 512 * 1024); // 512K [4096,64]
    ushort* Lbf  = (ushort*)(ws + 57 * MB);           // 512K latent bf16
    float*  sq_t = (float*)(ws + 59 * MB);            // 16KB
    float*  sq_l = (float*)(ws + 59 * MB + 16384);    // 16KB
    float*  acc3 = (float*)(ws + 59 * MB + 32768);    // 3 accumulators @ 64B stride
    ushort* Tbf  = (ushort*)(ws + 59 * MB + 65536);   // 512K tsamp bf16

    // pre-pass: all conversions, transposes, tsamp sqnorms, accumulator zeroing
    k_pre<<<13056, 256, 0, stream>>>(hidden, A1bf, tsamp, Tbf, sq_t, acc3,
                                     enc_w1, W1t, enc_w2, W2t,
                                     dec_w1, W3t, dec_w2, W4t);

    // encoder: GEMM1 pipelined 256x128 (NS=4 config -- NS=8 regressed in R5),
    // 512 blocks, 8x4 XCD chunks
    k_gemm256<128, 0, 8, 4><<<dim3(32, 16, 1), 512, 0, stream>>>(
        A1bf, W1t, enc_b1, H1bf, nullptr, 4096, 4096, 1024, 1024);
    // GEMM2 split-K=16: 512 blocks = 2/CU (memory-bound, old structure)
    k_gemm<64, 2, false><<<dim3(1, 32, 16), 256, 0, stream>>>(
        H1bf, W2t, nullptr, part, nullptr, 4096, 64, 4096, 256);
    k_ln64_red<<<1024, 256, 0, stream>>>(part, 16, enc_b2, enc_ln_g, enc_ln_b,
                                         latent_f, Lbf, sq_l);

    // decoder: GEMM3 K=64 (write-bound, old structure)
    k_gemm<64, 0, false><<<dim3(64, 32, 1), 256, 0, stream>>>(
        Lbf, W3t, dec_b1, H1bf, nullptr, 4096, 4096, 64, 64);
    // GEMM4: pipelined 256x128, split-K=2 -> 8x16x2 = 256 blocks, 8x4 chunks
    k_gemm256<128, 2, 8, 4><<<dim3(8, 16, 2), 512, 0, stream>>>(
        H1bf, W4t, nullptr, h4p0, recon, 4096, 1024, 4096, 2048);
    k_ln1024_red<<<4096, 256, 0, stream>>>(h4p0, recon, dec_b2, dec_ln_g,
                                           dec_ln_b, recon);

    // MMD: grams (separate-line accumulators), then tiny finalize
    k_gram_all<<<2080, 256, 0, stream>>>(Tbf, Lbf, sq_t, sq_l, acc3);
    k_finalize<<<1, 1, 0, stream>>>(acc3, reg);
}

// Round 7
// 270.117 us; speedup vs baseline: 1.0419x; 1.0419x over previous
//
#include <hip/hip_runtime.h>
#include <hip/hip_bf16.h>
#include <math.h>

// ---------------------------------------------------------------------------
// MMD-VAE fused pipeline for MI355X (gfx950)
// B=8 S=512 D=1024 DI=4096 DL=64, Nrows = B*S = 4096
// Outputs: recon [4096,1024] f32, latent [4096,64] f32, reg_loss scalar f32
// ---------------------------------------------------------------------------

typedef __attribute__((ext_vector_type(8))) short short8;    // 8 bf16 = 4 VGPR
typedef __attribute__((ext_vector_type(4))) float float4a;   // MFMA accum
typedef __attribute__((ext_vector_type(4))) unsigned short us4;

__device__ inline ushort bf16r(float x) {
    union { float f; unsigned u; } c; c.f = x;
    unsigned r = (c.u + 0x7fffu + ((c.u >> 16) & 1u)) >> 16;
    return (ushort)r;
}

// async global->LDS, 16B per lane, LDS dst = wave-uniform base + lane*16
__device__ inline void gld_lds16(const void* g, void* l) {
    __builtin_amdgcn_global_load_lds(
        (const __attribute__((address_space(1))) void*)g,
        (__attribute__((address_space(3))) void*)l, 16, 0, 0);
}

template <int N> __device__ inline void wait_vmcnt() {
    if constexpr (N == 0) asm volatile("s_waitcnt vmcnt(0)" ::: "memory");
    else if constexpr (N == 4) asm volatile("s_waitcnt vmcnt(4)" ::: "memory");
    else if constexpr (N == 6) asm volatile("s_waitcnt vmcnt(6)" ::: "memory");
}

template <int N> __device__ inline void wait_lgkmcnt() {
    if constexpr (N == 0) asm volatile("s_waitcnt lgkmcnt(0)" ::: "memory");
    else if constexpr (N == 2) asm volatile("s_waitcnt lgkmcnt(2)" ::: "memory");
    else if constexpr (N == 4) asm volatile("s_waitcnt lgkmcnt(4)" ::: "memory");
    else if constexpr (N == 6) asm volatile("s_waitcnt lgkmcnt(6)" ::: "memory");
    else if constexpr (N == 8) asm volatile("s_waitcnt lgkmcnt(8)" ::: "memory");
    else if constexpr (N == 12) asm volatile("s_waitcnt lgkmcnt(12)" ::: "memory");
}

// runtime-form counted wait: N is constant-folded after full unroll
__device__ inline void wait_lgkm_dyn(int n) {
    if (n == 0) wait_lgkmcnt<0>();
    else if (n == 2) wait_lgkmcnt<2>();
    else if (n == 4) wait_lgkmcnt<4>();
    else if (n == 6) wait_lgkmcnt<6>();
    else wait_lgkmcnt<8>();
}

// tanh-form gelu via sigmoid identity: 0.5v(1+tanh(z)) = v*sigmoid(2z).
// 2z = 1.5957691*v + 0.07135482*v^3.  |err| <~1e-3 (<< bf16 rounding here).
__device__ inline float fast_gelu(float v) {
    float v2 = v * v;
    float u = v * __builtin_fmaf(0.07135481627f, v2, 1.5957691216f);
    u = fminf(u, 30.0f);                       // overflow guard
    float e = __expf(u);
    return v * e * __builtin_amdgcn_rcpf(e + 1.0f);
}

// ---------------- fused pre-pass: conversions + transposes + zeroing -------
// Transpose section (R7): 64 in-rows x 32 in-cols tiles; each thread packs
// ushort2 -> 128B per half-wave output segment (was 64B).  LDS [32][65] f32
// pad -> conflict-free writes, 2-way (free) reads.
__global__ __launch_bounds__(256) void k_pre(
        const float* __restrict__ hidden, ushort* __restrict__ A1bf,
        const float* __restrict__ tsamp, ushort* __restrict__ Tbf,
        float* __restrict__ sq_t, float* __restrict__ acc,
        const float* __restrict__ i0, ushort* __restrict__ o0,
        const float* __restrict__ i1, ushort* __restrict__ o1,
        const float* __restrict__ i2, ushort* __restrict__ o2,
        const float* __restrict__ i3, ushort* __restrict__ o3) {
    int b = blockIdx.x, tid = threadIdx.x;
    if (b == 0 && tid < 24) acc[tid] = 0.0f;   // 3 accumulators, 1 per line
    if (b < 4096) {
        int i = b * 1024 + tid * 4;
        float4 v = *(const float4*)(hidden + i);
        us4 o = {bf16r(v.x), bf16r(v.y), bf16r(v.z), bf16r(v.w)};
        *(us4*)(A1bf + i) = o;
        return;
    }
    if (b < 4352) {
        int i = (b - 4096) * 1024 + tid * 4;
        float4 v = *(const float4*)(tsamp + i);
        us4 o = {bf16r(v.x), bf16r(v.y), bf16r(v.z), bf16r(v.w)};
        *(us4*)(Tbf + i) = o;
        float s = v.x * v.x + v.y * v.y + v.z * v.z + v.w * v.w;
#pragma unroll
        for (int off = 8; off; off >>= 1) s += __shfl_xor(s, off);
        if ((tid & 15) == 0) sq_t[i >> 6] = s;
        return;
    }
    // transpose section: in [Rin][C] f32 -> out [C][Rin] bf16 (R = Rin)
    __shared__ float t[32][65];
    const float* in; ushort* out; int R, C;
    int lb = b - 4352;
    if (lb < 2048)      { in = i0; out = o0; R = 1024; C = 4096; }
    else if (lb < 2176) { in = i1; out = o1; R = 4096; C = 64;   lb -= 2048; }
    else if (lb < 2304) { in = i2; out = o2; R = 64;   C = 4096; lb -= 2176; }
    else                { in = i3; out = o3; R = 4096; C = 1024; lb -= 2304; }
    int bx = (lb % (C / 32)) * 32;   // in-col base
    int by = (lb / (C / 32)) * 64;   // in-row base
    int tx = tid & 31, ty = tid >> 5;   // ty 0..7
#pragma unroll
    for (int i = 0; i < 64; i += 8)
        t[tx][i + ty] = in[(size_t)(by + i + ty) * C + (bx + tx)];
    __syncthreads();
#pragma unroll
    for (int i = 0; i < 32; i += 8) {
        int c = i + ty;
        ushort2 o;
        o.x = bf16r(t[c][2 * tx]);
        o.y = bf16r(t[c][2 * tx + 1]);
        *(ushort2*)(&out[(size_t)(bx + c) * R + by + 2 * tx]) = o;
    }
}

// ---------------- MFMA GEMM (2-barrier structure, kept for GEMM2/GEMM3) ----
// BM=128, BK=64, LDK=64, XOR swizzle k8^=row&7 on staging + read (0 bank
// conflicts).  BN=64: 4x1 waves of 32x64.
// EPI 0: +bias, gelu -> bf16 out.   EPI 1: +bias -> f32 out.
// EPI 2: raw fp32 partial (split-K): z==0 -> Out, z>0 -> Out2 if given.
template <int BN, int EPI, bool SWZ>
__global__ __launch_bounds__(256) void k_gemm(
        const ushort* __restrict__ A, const ushort* __restrict__ Bt,
        const float* __restrict__ bias, void* __restrict__ Out,
        float* __restrict__ Out2, int M, int N, int K, int KC) {
    constexpr int BM = 128, BK = 64;
    constexpr int WAVES_N = BN / 64;
    constexpr int WAVES_M = 4 / WAVES_N;
    constexpr int WM = BM / WAVES_M;
    constexpr int MT = WM / 16;
    constexpr int NT = 4;
    constexpr int CA = BM / 32, CB = BN / 32;

    __shared__ ushort sA[BM * 64];
    __shared__ ushort sB[BN * 64];

    const int tid  = threadIdx.x;
    const int wave = tid >> 6, lane = tid & 63;
    const int wm = wave / WAVES_N, wn = wave % WAVES_N;
    int bx = blockIdx.x, by = blockIdx.y;
    if constexpr (SWZ) {
        int lin = blockIdx.x + gridDim.x * blockIdx.y;
        by = lin % gridDim.y;          // m-tile fast => same XCD per A-row
        bx = lin / gridDim.y;
    }
    const int m0 = by * BM, n0 = bx * BN;
    const int lrow = lane & 15, lq = lane >> 4;
    const int srow8 = lane >> 3;
    const int sk8   = lane & 7;
    const int kbeg = blockIdx.z * KC;

    const ushort* pA[CA]; unsigned lA[CA];
#pragma unroll
    for (int j = 0; j < CA; ++j) {
        int c = wave * CA + j;
        int r = c * 8 + srow8;
        pA[j] = &A[(size_t)(m0 + r) * K + kbeg + ((sk8 ^ (r & 7)) * 8)];
        lA[j] = c * 512;
    }
    const ushort* pB[CB]; unsigned lB[CB];
#pragma unroll
    for (int j = 0; j < CB; ++j) {
        int c = wave * CB + j;
        int r = c * 8 + srow8;
        pB[j] = &Bt[(size_t)(n0 + r) * K + kbeg + ((sk8 ^ (r & 7)) * 8)];
        lB[j] = c * 512;
    }
    unsigned aoff[2][MT], boff[2][NT];
#pragma unroll
    for (int h = 0; h < 2; ++h) {
#pragma unroll
        for (int mt = 0; mt < MT; ++mt) {
            int r = wm * WM + mt * 16 + lrow;
            aoff[h][mt] = r * 64 + (((h * 4 + lq) ^ (r & 7)) * 8);
        }
#pragma unroll
        for (int nt = 0; nt < NT; ++nt) {
            int r = wn * 64 + nt * 16 + lrow;
            boff[h][nt] = r * 64 + (((h * 4 + lq) ^ (r & 7)) * 8);
        }
    }

    float4a acc[MT][NT];
#pragma unroll
    for (int mt = 0; mt < MT; ++mt)
#pragma unroll
        for (int nt = 0; nt < NT; ++nt)
            acc[mt][nt] = (float4a){0.f, 0.f, 0.f, 0.f};

    for (int k0 = 0; k0 < KC; k0 += BK) {
#pragma unroll
        for (int j = 0; j < CA; ++j) {
            gld_lds16(pA[j], &sA[lA[j]]);
            pA[j] += BK;
        }
#pragma unroll
        for (int j = 0; j < CB; ++j) {
            gld_lds16(pB[j], &sB[lB[j]]);
            pB[j] += BK;
        }
        __syncthreads();
#pragma unroll
        for (int h = 0; h < 2; ++h) {
            short8 af[MT], bfr[NT];
#pragma unroll
            for (int mt = 0; mt < MT; ++mt)
                af[mt] = *(short8*)(&sA[aoff[h][mt]]);
#pragma unroll
            for (int nt = 0; nt < NT; ++nt)
                bfr[nt] = *(short8*)(&sB[boff[h][nt]]);
#pragma unroll
            for (int mt = 0; mt < MT; ++mt)
#pragma unroll
                for (int nt = 0; nt < NT; ++nt)
                    acc[mt][nt] = __builtin_amdgcn_mfma_f32_16x16x32_bf16(
                        af[mt], bfr[nt], acc[mt][nt], 0, 0, 0);
        }
        __syncthreads();
    }

    float* dstp = nullptr;
    if constexpr (EPI == 2) {
        if (Out2 && blockIdx.z) dstp = Out2;
        else dstp = (float*)Out + (size_t)blockIdx.z * M * N;
    }
#pragma unroll
    for (int mt = 0; mt < MT; ++mt)
#pragma unroll
        for (int nt = 0; nt < NT; ++nt) {
            int col = n0 + wn * 64 + nt * 16 + lrow;
            float bv = 0.f;
            if constexpr (EPI != 2) bv = bias[col];
#pragma unroll
            for (int r = 0; r < 4; ++r) {
                int row = m0 + wm * WM + mt * 16 + lq * 4 + r;
                float v = acc[mt][nt][r] + bv;
                if constexpr (EPI == 0) {
                    ((ushort*)Out)[(size_t)row * N + col] = bf16r(fast_gelu(v));
                } else if constexpr (EPI == 1) {
                    ((float*)Out)[(size_t)row * N + col] = v;
                } else {
                    dstp[(size_t)row * N + col] = v;
                }
            }
        }
}

// ---------------- min-barrier 256-row GEMM (R4-proven, for GEMM1) ----------
// BM=256, BK=64, 512 threads = 8 waves, double-buffered LDS, XOR-slot
// swizzle.  ONE barrier per K-tile, counted waits, all issues front-loaded:
//   per tile t (buf d = t&1): read af0+bfr0 | af1+bfr1 | stage t+1 -> d^1 |
//   lgkm(MT+4) | MFMA h0 | lgkm(0) | MFMA h1 | vmcnt(0)+barrier.
// R4 measured ~40us for BN=256 (4096x4096x1024).  LDS 131072 (distinct
// signature from the step-pipe kernel for counter attribution).
template <int BN, int EPI, int CX, int CY>
__global__ __launch_bounds__(512, 2) void k_gemm256mb(
        const ushort* __restrict__ A, const ushort* __restrict__ Bt,
        const float* __restrict__ bias, void* __restrict__ Out,
        float* __restrict__ Out2, int M, int N, int K, int KC) {
    constexpr int BM = 256, BK = 64;
    constexpr int AI = 4;
    constexpr int BI = BN / 64;
    constexpr int WAVES_N = BN / 64;         // 4
    constexpr int WAVES_M = 8 / WAVES_N;     // 2
    constexpr int WM = BM / WAVES_M;         // 128
    constexpr int MT = WM / 16;              // 8
    constexpr int NT = 4;

    __shared__ ushort sA[2][BM * 64];
    __shared__ ushort sB[2][BN * 64];

    const int tid = threadIdx.x;
    const int wave = tid >> 6, lane = tid & 63;
    const int wm = wave / WAVES_N, wn = wave % WAVES_N;

    // ---- chunked XCD swizzle (bijective: nwg % 8 == 0 by construction) ----
    const int gx = gridDim.x, gy = gridDim.y;
    const int lin = blockIdx.x + gx * (blockIdx.y + gy * blockIdx.z);
    const int nwg = gx * gy * gridDim.z;
    const int cpx = nwg >> 3;
    const int swz = (lin & 7) * cpx + (lin >> 3);
    const int nz  = gx * gy;
    const int zz  = swz / nz;
    const int rr  = swz % nz;
    const int chunk = rr / (CX * CY);
    const int lcl   = rr % (CX * CY);
    const int ncx   = gx / CX;
    const int bx = (chunk % ncx) * CX + (lcl % CX);
    const int by = (chunk / ncx) * CY + (lcl / CX);

    const int m0 = by * BM, n0 = bx * BN;
    const int lrow = lane & 15, lq = lane >> 4;
    const int kbeg = zz * KC;
    const int nT = KC / BK;

    const int crow = tid >> 3;
    const int ck8  = (tid & 7) ^ (crow & 7);
    const ushort* pAbase = A  + (size_t)(m0 + crow) * K + kbeg + ck8 * 8;
    const ushort* pBbase = Bt + (size_t)(n0 + crow) * K + kbeg + ck8 * 8;

    const int a0  = (wm * WM + lrow) * 64;
    const int b0  = (wn * 64 + lrow) * 64;
    const int sw0 = ((lq) ^ (lrow & 7)) * 8;
    const int sw1 = ((4 + lq) ^ (lrow & 7)) * 8;

    float4a acc[MT][NT];
#pragma unroll
    for (int mt = 0; mt < MT; ++mt)
#pragma unroll
        for (int nt = 0; nt < NT; ++nt)
            acc[mt][nt] = (float4a){0.f, 0.f, 0.f, 0.f};

    // prologue: tile 0 -> buf 0
#pragma unroll
    for (int j = 0; j < AI; ++j)
        gld_lds16(pAbase + (size_t)j * 64 * K, &sA[0][j * 4096 + wave * 512]);
#pragma unroll
    for (int j = 0; j < BI; ++j)
        gld_lds16(pBbase + (size_t)j * 64 * K, &sB[0][j * 4096 + wave * 512]);
    wait_vmcnt<0>();
    __builtin_amdgcn_s_barrier();
    __builtin_amdgcn_sched_barrier(0);

    for (int t = 0; t < nT; ++t) {
        const int d = t & 1;
        const bool pf1 = (t + 1 < nT);
        const size_t koff1 = (size_t)(t + 1) * BK;

        short8 af0[MT], bfr0[NT], af1[MT], bfr1[NT];
#pragma unroll
        for (int mt = 0; mt < MT; ++mt)
            af0[mt] = *(const short8*)(&sA[d][a0 + mt * 1024 + sw0]);
#pragma unroll
        for (int nt = 0; nt < NT; ++nt)
            bfr0[nt] = *(const short8*)(&sB[d][b0 + nt * 1024 + sw0]);
        __builtin_amdgcn_sched_barrier(0);   // pin order: h0 batch first
#pragma unroll
        for (int mt = 0; mt < MT; ++mt)
            af1[mt] = *(const short8*)(&sA[d][a0 + mt * 1024 + sw1]);
#pragma unroll
        for (int nt = 0; nt < NT; ++nt)
            bfr1[nt] = *(const short8*)(&sB[d][b0 + nt * 1024 + sw1]);
        if (pf1) {                            // stage t+1 into dead buffer
#pragma unroll
            for (int j = 0; j < AI; ++j)
                gld_lds16(pAbase + (size_t)j * 64 * K + koff1,
                          &sA[d ^ 1][j * 4096 + wave * 512]);
#pragma unroll
            for (int j = 0; j < BI; ++j)
                gld_lds16(pBbase + (size_t)j * 64 * K + koff1,
                          &sB[d ^ 1][j * 4096 + wave * 512]);
        }
        wait_lgkmcnt<MT + 4>();               // af0+bfr0 complete
        __builtin_amdgcn_sched_barrier(0);
        __builtin_amdgcn_s_setprio(1);
#pragma unroll
        for (int mt = 0; mt < MT; ++mt)
#pragma unroll
            for (int nt = 0; nt < NT; ++nt)
                acc[mt][nt] = __builtin_amdgcn_mfma_f32_16x16x32_bf16(
                    af0[mt], bfr0[nt], acc[mt][nt], 0, 0, 0);
        __builtin_amdgcn_s_setprio(0);
        wait_lgkmcnt<0>();                    // af1+bfr1 complete
        __builtin_amdgcn_sched_barrier(0);
        __builtin_amdgcn_s_setprio(1);
#pragma unroll
        for (int mt = 0; mt < MT; ++mt)
#pragma unroll
            for (int nt = 0; nt < NT; ++nt)
                acc[mt][nt] = __builtin_amdgcn_mfma_f32_16x16x32_bf16(
                    af1[mt], bfr1[nt], acc[mt][nt], 0, 0, 0);
        __builtin_amdgcn_s_setprio(0);
        if (pf1) {                            // boundary: the only barrier
            wait_vmcnt<0>();
            __builtin_amdgcn_s_barrier();
            __builtin_amdgcn_sched_barrier(0);
        }
    }

    // epilogue
    float* dstp = nullptr;
    if constexpr (EPI == 2) {
        if (Out2 && zz) dstp = Out2;
        else dstp = (float*)Out + (size_t)zz * M * N;
    }
#pragma unroll
    for (int mt = 0; mt < MT; ++mt)
#pragma unroll
        for (int nt = 0; nt < NT; ++nt) {
            const int col = n0 + wn * 64 + nt * 16 + lrow;
            float bv = 0.f;
            if constexpr (EPI == 0) bv = bias[col];
#pragma unroll
            for (int r = 0; r < 4; ++r) {
                const int row = m0 + wm * WM + mt * 16 + lq * 4 + r;
                float v = acc[mt][nt][r] + bv;
                if constexpr (EPI == 0)
                    ((ushort*)Out)[(size_t)row * N + col] = bf16r(fast_gelu(v));
                else
                    dstp[(size_t)row * N + col] = v;
            }
        }
}

// ---------------- step-pipelined 256-row GEMM (R5-proven, for GEMM4) -------
// BM=256, BN=128, BK=64, 8 waves, NS=4 steps/tile: issue step s+2's reads
// (2 ds_read, +NT at k-half start), counted lgkmcnt, 8 MFMAs.  LDS pipe gets
// fresh work every step while MFMAs run.  R5 measured ~19-20us for
// 4096x1024x4096 split-K=2.  NS=8 (BN=256) REGRESSED -- do not use.
template <int BN, int EPI, int CX, int CY>
__global__ __launch_bounds__(512, 2) void k_gemm256sp(
        const ushort* __restrict__ A, const ushort* __restrict__ Bt,
        const float* __restrict__ bias, void* __restrict__ Out,
        float* __restrict__ Out2, int M, int N, int K, int KC) {
    constexpr int BM = 256, BK = 64;
    constexpr int AI = 4;
    constexpr int BI = BN / 64;              // 2
    constexpr int WAVES_N = BN / 64;         // 2
    constexpr int WAVES_M = 8 / WAVES_N;     // 4
    constexpr int WM = BM / WAVES_M;         // 64
    constexpr int MT = WM / 16;              // 4
    constexpr int NT = 4;
    constexpr int NS = MT;                   // 4
    constexpr int NS2 = MT / 2;              // 2

    __shared__ ushort sA[2][BM * 64];
    __shared__ ushort sB[2][BN * 64];

    const int tid = threadIdx.x;
    const int wave = tid >> 6, lane = tid & 63;
    const int wm = wave / WAVES_N, wn = wave % WAVES_N;

    const int gx = gridDim.x, gy = gridDim.y;
    const int lin = blockIdx.x + gx * (blockIdx.y + gy * blockIdx.z);
    const int nwg = gx * gy * gridDim.z;
    const int cpx = nwg >> 3;
    const int swz = (lin & 7) * cpx + (lin >> 3);
    const int nz  = gx * gy;
    const int zz  = swz / nz;
    const int rr  = swz % nz;
    const int chunk = rr / (CX * CY);
    const int lcl   = rr % (CX * CY);
    const int ncx   = gx / CX;
    const int bx = (chunk % ncx) * CX + (lcl % CX);
    const int by = (chunk / ncx) * CY + (lcl / CX);

    const int m0 = by * BM, n0 = bx * BN;
    const int lrow = lane & 15, lq = lane >> 4;
    const int kbeg = zz * KC;
    const int nT = KC / BK;

    const int crow = tid >> 3;
    const int ck8  = (tid & 7) ^ (crow & 7);
    const ushort* pAbase = A  + (size_t)(m0 + crow) * K + kbeg + ck8 * 8;
    const ushort* pBbase = Bt + (size_t)(n0 + crow) * K + kbeg + ck8 * 8;

    const int a0  = (wm * WM + lrow) * 64;
    const int b0  = (wn * 64 + lrow) * 64;
    const int sw0 = ((lq) ^ (lrow & 7)) * 8;
    const int sw1 = ((4 + lq) ^ (lrow & 7)) * 8;

    float4a acc[MT][NT];
#pragma unroll
    for (int mt = 0; mt < MT; ++mt)
#pragma unroll
        for (int nt = 0; nt < NT; ++nt)
            acc[mt][nt] = (float4a){0.f, 0.f, 0.f, 0.f};

    // prologue: tile 0 -> buf 0
#pragma unroll
    for (int j = 0; j < AI; ++j)
        gld_lds16(pAbase + (size_t)j * 64 * K, &sA[0][j * 4096 + wave * 512]);
#pragma unroll
    for (int j = 0; j < BI; ++j)
        gld_lds16(pBbase + (size_t)j * 64 * K, &sB[0][j * 4096 + wave * 512]);
    wait_vmcnt<0>();
    __builtin_amdgcn_s_barrier();
    __builtin_amdgcn_sched_barrier(0);

    for (int t = 0; t < nT; ++t) {
        const int d = t & 1;
        const bool pf1 = (t + 1 < nT);
        const size_t koff1 = (size_t)(t + 1) * BK;

        short8 af[NS][2], bfr[2][NT];

        // S0: bfr[h=0] + af[0]
#pragma unroll
        for (int nt = 0; nt < NT; ++nt)
            bfr[0][nt] = *(const short8*)(&sB[d][b0 + nt * 1024 + sw0]);
        af[0][0] = *(const short8*)(&sA[d][a0 + 0 * 1024 + sw0]);
        af[0][1] = *(const short8*)(&sA[d][a0 + 1 * 1024 + sw0]);
        __builtin_amdgcn_sched_barrier(0);
        // S1: af[1]
        af[1][0] = *(const short8*)(&sA[d][a0 + 2 * 1024 + sw0]);
        af[1][1] = *(const short8*)(&sA[d][a0 + 3 * 1024 + sw0]);
        __builtin_amdgcn_sched_barrier(0);
        if (pf1) {                            // stage t+1 into dead buffer
#pragma unroll
            for (int j = 0; j < AI; ++j)
                gld_lds16(pAbase + (size_t)j * 64 * K + koff1,
                          &sA[d ^ 1][j * 4096 + wave * 512]);
#pragma unroll
            for (int j = 0; j < BI; ++j)
                gld_lds16(pBbase + (size_t)j * 64 * K + koff1,
                          &sB[d ^ 1][j * 4096 + wave * 512]);
        }
        __builtin_amdgcn_sched_barrier(0);

#pragma unroll
        for (int s = 0; s < NS; ++s) {
            const int s2 = s + 2;
            if (s2 < NS) {                    // issue step s+2's reads
                const int h2 = s2 / NS2;
                const int mb2 = (s2 % NS2) * 2;
                const int swh2 = h2 ? sw1 : sw0;
                if ((s2 % NS2) == 0) {
#pragma unroll
                    for (int nt = 0; nt < NT; ++nt)
                        bfr[h2][nt] =
                            *(const short8*)(&sB[d][b0 + nt * 1024 + swh2]);
                }
                af[s2][0] = *(const short8*)(&sA[d][a0 + (mb2 + 0) * 1024 + swh2]);
                af[s2][1] = *(const short8*)(&sA[d][a0 + (mb2 + 1) * 1024 + swh2]);
                __builtin_amdgcn_sched_barrier(0);
            }
            int Ns = 0;
            if (s + 1 < NS) Ns += (((s + 1) % NS2) == 0) ? (2 + NT) : 2;
            if (s + 2 < NS) Ns += (((s + 2) % NS2) == 0) ? (2 + NT) : 2;
            wait_lgkm_dyn(Ns);
            __builtin_amdgcn_sched_barrier(0);
            const int h = s / NS2, mb = (s % NS2) * 2;
            __builtin_amdgcn_s_setprio(1);
#pragma unroll
            for (int i = 0; i < 2; ++i)
#pragma unroll
                for (int nt = 0; nt < NT; ++nt)
                    acc[mb + i][nt] = __builtin_amdgcn_mfma_f32_16x16x32_bf16(
                        af[s][i], bfr[h][nt], acc[mb + i][nt], 0, 0, 0);
            __builtin_amdgcn_s_setprio(0);
        }
        if (pf1) {                            // boundary: the only barrier
            wait_vmcnt<0>();
            __builtin_amdgcn_s_barrier();
            __builtin_amdgcn_sched_barrier(0);
        }
    }

    // epilogue
    float* dstp = nullptr;
    if constexpr (EPI == 2) {
        if (Out2 && zz) dstp = Out2;
        else dstp = (float*)Out + (size_t)zz * M * N;
    }
#pragma unroll
    for (int mt = 0; mt < MT; ++mt)
#pragma unroll
        for (int nt = 0; nt < NT; ++nt) {
            const int col = n0 + wn * 64 + nt * 16 + lrow;
            float bv = 0.f;
            if constexpr (EPI == 0) bv = bias[col];
#pragma unroll
            for (int r = 0; r < 4; ++r) {
                const int row = m0 + wm * WM + mt * 16 + lq * 4 + r;
                float v = acc[mt][nt][r] + bv;
                if constexpr (EPI == 0)
                    ((ushort*)Out)[(size_t)row * N + col] = bf16r(fast_gelu(v));
                else
                    dstp[(size_t)row * N + col] = v;
            }
        }
}

// ---------------- fused MMD grams (separate-line accumulators) -------------
// blocks 0..527: tt upper-triangle tiles; 528..1055: ll; 1056..2079: tl full.
// Off-diagonal symmetric tiles weighted 2x; diagonal tiles exact (incl i==j).
__global__ __launch_bounds__(256) void k_gram_all(
        const ushort* __restrict__ Tbf, const ushort* __restrict__ Lbf,
        const float* __restrict__ sq_t, const float* __restrict__ sq_l,
        float* __restrict__ accum) {
    __shared__ ushort sX[128 * 64];
    __shared__ ushort sY[128 * 64];
    __shared__ float red[4];

    int id = blockIdx.x;
    int pair, tbx, tby; float w;
    if (id < 1056) {
        pair = (id < 528) ? 0 : 1;
        int t = (pair == 0) ? id : id - 528;
        int r = (int)((sqrtf(8.0f * t + 1.0f) - 1.0f) * 0.5f);
        while ((r + 1) * (r + 2) / 2 <= t) ++r;
        while (r * (r + 1) / 2 > t) --r;
        tby = r; tbx = t - r * (r + 1) / 2;
        w = (tbx == tby) ? 1.0f : 2.0f;
    } else {
        pair = 2; int t = id - 1056;
        tbx = t & 31; tby = t >> 5; w = 1.0f;
    }
    const ushort* Xb = (pair == 1) ? Lbf : Tbf;
    const ushort* Yb = (pair == 0) ? Tbf : Lbf;
    const float* sqX = (pair == 1) ? sq_l : sq_t;
    const float* sqY = (pair == 0) ? sq_t : sq_l;

    const int tid  = threadIdx.x;
    const int wave = tid >> 6, lane = tid & 63;
    const int wm = wave >> 1, wn = wave & 1;
    const int bx = tbx * 128, by = tby * 128;
    const int lrow = lane & 15, lq = lane >> 4;
    const int srow8 = lane >> 3, sk8 = lane & 7;

#pragma unroll
    for (int j = 0; j < 4; ++j) {
        int c = wave * 4 + j;
        int r = c * 8 + srow8;
        int kc = (sk8 ^ (r & 7)) * 8;
        gld_lds16(&Xb[(size_t)(bx + r) * 64 + kc], &sX[c * 512]);
        gld_lds16(&Yb[(size_t)(by + r) * 64 + kc], &sY[c * 512]);
    }

    unsigned xoff[2][4], yoff[2][4];
#pragma unroll
    for (int h = 0; h < 2; ++h)
#pragma unroll
        for (int i = 0; i < 4; ++i) {
            int rx = wm * 64 + i * 16 + lrow;
            int ry = wn * 64 + i * 16 + lrow;
            xoff[h][i] = rx * 64 + (((h * 4 + lq) ^ (rx & 7)) * 8);
            yoff[h][i] = ry * 64 + (((h * 4 + lq) ^ (ry & 7)) * 8);
        }
    __syncthreads();

    float4a acc[4][4];
#pragma unroll
    for (int mt = 0; mt < 4; ++mt)
#pragma unroll
        for (int nt = 0; nt < 4; ++nt)
            acc[mt][nt] = (float4a){0.f, 0.f, 0.f, 0.f};

#pragma unroll
    for (int h = 0; h < 2; ++h) {
        short8 xf[4], yf[4];
#pragma unroll
        for (int mt = 0; mt < 4; ++mt)
            xf[mt] = *(short8*)(&sX[xoff[h][mt]]);
#pragma unroll
        for (int nt = 0; nt < 4; ++nt)
            yf[nt] = *(short8*)(&sY[yoff[h][nt]]);
#pragma unroll
        for (int mt = 0; mt < 4; ++mt)
#pragma unroll
            for (int nt = 0; nt < 4; ++nt)
                acc[mt][nt] = __builtin_amdgcn_mfma_f32_16x16x32_bf16(
                    xf[mt], yf[nt], acc[mt][nt], 0, 0, 0);
    }

    float sy[4];
#pragma unroll
    for (int nt = 0; nt < 4; ++nt)
        sy[nt] = sqY[by + wn * 64 + nt * 16 + lrow];
    float s = 0.f;
#pragma unroll
    for (int mt = 0; mt < 4; ++mt)
#pragma unroll
        for (int r = 0; r < 4; ++r) {
            float sx = sqX[bx + wm * 64 + mt * 16 + lq * 4 + r];
#pragma unroll
            for (int nt = 0; nt < 4; ++nt)
                s += __expf((2.0f * acc[mt][nt][r] - sx - sy[nt]) * (1.0f / 4096.0f));
        }
    s *= w;
#pragma unroll
    for (int off = 32; off; off >>= 1) s += __shfl_xor(s, off);
    if ((tid & 63) == 0) red[tid >> 6] = s;
    __syncthreads();
    if (tid == 0) atomicAdd(accum + pair * 8, red[0] + red[1] + red[2] + red[3]);
}

// ---------------- LayerNorm over 64, split-K reduce, + latent sqnorm -------
__global__ __launch_bounds__(256) void k_ln64_red(
        const float* __restrict__ part, int npart,
        const float* __restrict__ bias, const float* __restrict__ g,
        const float* __restrict__ b, float* __restrict__ outf,
        ushort* __restrict__ outb, float* __restrict__ sq_l) {
    int wave = threadIdx.x >> 6, lane = threadIdx.x & 63;
    int row = blockIdx.x * 4 + wave;
    float x = bias[lane];
    for (int s = 0; s < npart; ++s)
        x += part[(size_t)s * 4096 * 64 + row * 64 + lane];
    float s = x;
#pragma unroll
    for (int off = 32; off; off >>= 1) s += __shfl_xor(s, off);
    float mu = s * (1.0f / 64.0f);
    float d = x - mu;
    float v = d * d;
#pragma unroll
    for (int off = 32; off; off >>= 1) v += __shfl_xor(v, off);
    float rs = rsqrtf(v * (1.0f / 64.0f) + 1e-9f);
    float y = d * rs * g[lane] + b[lane];
    outf[row * 64 + lane] = y;
    outb[row * 64 + lane] = bf16r(y);
    float q = y * y;
#pragma unroll
    for (int off = 32; off; off >>= 1) q += __shfl_xor(q, off);
    if (lane == 0) sq_l[row] = q;
}

// ---------------- LayerNorm over 1024 with 2-partial reduce ----------------
// p1 may alias out (read-before-write within the same block/row).
__global__ __launch_bounds__(256) void k_ln1024_red(
        const float* __restrict__ p0, const float* __restrict__ p1,
        const float* __restrict__ bias, const float* __restrict__ g,
        const float* __restrict__ b, float* __restrict__ out) {
    __shared__ float red[4];
    int row = blockIdx.x, tid = threadIdx.x;
    const float4 v0 = *(const float4*)(p0 + (size_t)row * 1024 + tid * 4);
    const float4 v1 = *(const float4*)(p1 + (size_t)row * 1024 + tid * 4);
    const float4 bb = *(const float4*)(bias + tid * 4);
    float4 v;
    v.x = v0.x + v1.x + bb.x;
    v.y = v0.y + v1.y + bb.y;
    v.z = v0.z + v1.z + bb.z;
    v.w = v0.w + v1.w + bb.w;
    float s = v.x + v.y + v.z + v.w;
#pragma unroll
    for (int off = 32; off; off >>= 1) s += __shfl_xor(s, off);
    if ((tid & 63) == 0) red[tid >> 6] = s;
    __syncthreads();
    float mu = (red[0] + red[1] + red[2] + red[3]) * (1.0f / 1024.0f);
    float dx = v.x - mu, dy = v.y - mu, dz = v.z - mu, dw = v.w - mu;
    float q = dx * dx + dy * dy + dz * dz + dw * dw;
#pragma unroll
    for (int off = 32; off; off >>= 1) q += __shfl_xor(q, off);
    __syncthreads();
    if ((tid & 63) == 0) red[tid >> 6] = q;
    __syncthreads();
    float rs = rsqrtf((red[0] + red[1] + red[2] + red[3]) * (1.0f / 1024.0f) + 1e-9f);
    const float4 gv = *(const float4*)(g + tid * 4);
    const float4 bv = *(const float4*)(b + tid * 4);
    float4 o;
    o.x = dx * rs * gv.x + bv.x;
    o.y = dy * rs * gv.y + bv.y;
    o.z = dz * rs * gv.z + bv.z;
    o.w = dw * rs * gv.w + bv.w;
    *(float4*)(out + (size_t)row * 1024 + tid * 4) = o;
}

__global__ void k_finalize(const float* __restrict__ accum, float* __restrict__ out) {
    // km_i = accum_i / 4096^2 ; reg = (km0 + km1 - 2*km2) / B * S = mmd * 64
    out[0] = (accum[0] + accum[8] - 2.0f * accum[16]) * (64.0f / (4096.0f * 4096.0f));
}

// ---------------------------------------------------------------------------
extern "C" void kernel_launch(void* const* d_in, const int* in_sizes, int n_in,
                              void* d_out, int out_size, void* d_ws, size_t ws_size,
                              hipStream_t stream) {
    const float* hidden   = (const float*)d_in[0];
    const float* tsamp    = (const float*)d_in[1];
    const float* enc_w1   = (const float*)d_in[2];
    const float* enc_b1   = (const float*)d_in[3];
    const float* enc_w2   = (const float*)d_in[4];
    const float* enc_b2   = (const float*)d_in[5];
    const float* enc_ln_g = (const float*)d_in[6];
    const float* enc_ln_b = (const float*)d_in[7];
    const float* dec_w1   = (const float*)d_in[8];
    const float* dec_b1   = (const float*)d_in[9];
    const float* dec_w2   = (const float*)d_in[10];
    const float* dec_b2   = (const float*)d_in[11];
    const float* dec_ln_g = (const float*)d_in[12];
    const float* dec_ln_b = (const float*)d_in[13];

    float* out      = (float*)d_out;
    float* recon    = out;                 // 4096*1024
    float* latent_f = out + 4194304;       // 4096*64
    float* reg      = out + 4456448;       // scalar

    char* ws = (char*)d_ws;
    const size_t MB = 1024 * 1024;
    ushort* A1bf = (ushort*)(ws + 0);                 // 8MB  hidden bf16 (dead after GEMM1)
    ushort* W1t  = (ushort*)(ws + 8 * MB);            // 8MB  (dead after GEMM1)
    float*  part = (float*)(ws + 0);                  // 16MB GEMM2 split-K partials [16][4096,64]
    float*  h4p0 = (float*)(ws + 0);                  // 16MB GEMM4 partial z=0 (z=1 -> recon buf)
    ushort* H1bf = (ushort*)(ws + 16 * MB);           // 32MB enc hidden, later dec hidden
    ushort* W4t  = (ushort*)(ws + 48 * MB);           // 8MB  [1024,4096]
    ushort* W2t  = (ushort*)(ws + 56 * MB);           // 512K [64,4096]
    ushort* W3t  = (ushort*)(ws + 56 * MB + 512 * 1024); // 512K [4096,64]
    ushort* Lbf  = (ushort*)(ws + 57 * MB);           // 512K latent bf16
    float*  sq_t = (float*)(ws + 59 * MB);            // 16KB
    float*  sq_l = (float*)(ws + 59 * MB + 16384);    // 16KB
    float*  acc3 = (float*)(ws + 59 * MB + 32768);    // 3 accumulators @ 64B stride
    ushort* Tbf  = (ushort*)(ws + 59 * MB + 65536);   // 512K tsamp bf16

    // pre-pass: conversions, transposes (64x32 ushort2 tiles), sqnorms, zeroing
    k_pre<<<8704, 256, 0, stream>>>(hidden, A1bf, tsamp, Tbf, sq_t, acc3,
                                    enc_w1, W1t, enc_w2, W2t,
                                    dec_w1, W3t, dec_w2, W4t);

    // encoder: GEMM1 min-barrier 256x256 (R4-proven), 256 blocks = 1/CU
    k_gemm256mb<256, 0, 4, 8><<<dim3(16, 16, 1), 512, 0, stream>>>(
        A1bf, W1t, enc_b1, H1bf, nullptr, 4096, 4096, 1024, 1024);
    // GEMM2 split-K=16: 512 blocks = 2/CU (memory-bound, old structure)
    k_gemm<64, 2, false><<<dim3(1, 32, 16), 256, 0, stream>>>(
        H1bf, W2t, nullptr, part, nullptr, 4096, 64, 4096, 256);
    k_ln64_red<<<1024, 256, 0, stream>>>(part, 16, enc_b2, enc_ln_g, enc_ln_b,
                                         latent_f, Lbf, sq_l);

    // decoder: GEMM3 K=64 (write-bound, old structure)
    k_gemm<64, 0, false><<<dim3(64, 32, 1), 256, 0, stream>>>(
        Lbf, W3t, dec_b1, H1bf, nullptr, 4096, 4096, 64, 64);
    // GEMM4: step-pipelined 256x128 (R5-proven), split-K=2 -> 256 blocks
    k_gemm256sp<128, 2, 8, 4><<<dim3(8, 16, 2), 512, 0, stream>>>(
        H1bf, W4t, nullptr, h4p0, recon, 4096, 1024, 4096, 2048);
    k_ln1024_red<<<4096, 256, 0, stream>>>(h4p0, recon, dec_b2, dec_ln_g,
                                           dec_ln_b, recon);

    // MMD: grams (separate-line accumulators), then tiny finalize
    k_gram_all<<<2080, 256, 0, stream>>>(Tbf, Lbf, sq_t, sq_l, acc3);
    k_finalize<<<1, 1, 0, stream>>>(acc3, reg);
}

// Round 8
// 260.593 us; speedup vs baseline: 1.0799x; 1.0366x over previous
//
#include <hip/hip_runtime.h>
#include <hip/hip_bf16.h>
#include <math.h>

// ---------------------------------------------------------------------------
// MMD-VAE fused pipeline for MI355X (gfx950)
// B=8 S=512 D=1024 DI=4096 DL=64, Nrows = B*S = 4096
// Outputs: recon [4096,1024] f32, latent [4096,64] f32, reg_loss scalar f32
// ---------------------------------------------------------------------------

typedef __attribute__((ext_vector_type(8))) short short8;    // 8 bf16 = 4 VGPR
typedef __attribute__((ext_vector_type(4))) float float4a;   // MFMA accum
typedef __attribute__((ext_vector_type(4))) unsigned short us4;

__device__ inline ushort bf16r(float x) {
    union { float f; unsigned u; } c; c.f = x;
    unsigned r = (c.u + 0x7fffu + ((c.u >> 16) & 1u)) >> 16;
    return (ushort)r;
}

// async global->LDS, 16B per lane, LDS dst = wave-uniform base + lane*16
__device__ inline void gld_lds16(const void* g, void* l) {
    __builtin_amdgcn_global_load_lds(
        (const __attribute__((address_space(1))) void*)g,
        (__attribute__((address_space(3))) void*)l, 16, 0, 0);
}

template <int N> __device__ inline void wait_vmcnt() {
    if constexpr (N == 0) asm volatile("s_waitcnt vmcnt(0)" ::: "memory");
    else if constexpr (N == 4) asm volatile("s_waitcnt vmcnt(4)" ::: "memory");
    else if constexpr (N == 6) asm volatile("s_waitcnt vmcnt(6)" ::: "memory");
}

template <int N> __device__ inline void wait_lgkmcnt() {
    if constexpr (N == 0) asm volatile("s_waitcnt lgkmcnt(0)" ::: "memory");
    else if constexpr (N == 2) asm volatile("s_waitcnt lgkmcnt(2)" ::: "memory");
    else if constexpr (N == 4) asm volatile("s_waitcnt lgkmcnt(4)" ::: "memory");
    else if constexpr (N == 6) asm volatile("s_waitcnt lgkmcnt(6)" ::: "memory");
    else if constexpr (N == 8) asm volatile("s_waitcnt lgkmcnt(8)" ::: "memory");
    else if constexpr (N == 12) asm volatile("s_waitcnt lgkmcnt(12)" ::: "memory");
}

// tanh-form gelu via sigmoid identity: 0.5v(1+tanh(z)) = v*sigmoid(2z).
// 2z = 1.5957691*v + 0.07135482*v^3.  |err| <~1e-3 (<< bf16 rounding here).
__device__ inline float fast_gelu(float v) {
    float v2 = v * v;
    float u = v * __builtin_fmaf(0.07135481627f, v2, 1.5957691216f);
    u = fminf(u, 30.0f);                       // overflow guard
    float e = __expf(u);
    return v * e * __builtin_amdgcn_rcpf(e + 1.0f);
}

// ---------------- fused pre-pass: conversions + transposes + zeroing -------
__global__ __launch_bounds__(256) void k_pre(
        const float* __restrict__ hidden, ushort* __restrict__ A1bf,
        const float* __restrict__ tsamp, ushort* __restrict__ Tbf,
        float* __restrict__ sq_t, float* __restrict__ acc,
        const float* __restrict__ i0, ushort* __restrict__ o0,
        const float* __restrict__ i1, ushort* __restrict__ o1,
        const float* __restrict__ i2, ushort* __restrict__ o2,
        const float* __restrict__ i3, ushort* __restrict__ o3) {
    int b = blockIdx.x, tid = threadIdx.x;
    if (b == 0 && tid < 24) acc[tid] = 0.0f;   // 3 accumulators, 1 per line
    if (b < 4096) {
        int i = b * 1024 + tid * 4;
        float4 v = *(const float4*)(hidden + i);
        us4 o = {bf16r(v.x), bf16r(v.y), bf16r(v.z), bf16r(v.w)};
        *(us4*)(A1bf + i) = o;
        return;
    }
    if (b < 4352) {
        int i = (b - 4096) * 1024 + tid * 4;
        float4 v = *(const float4*)(tsamp + i);
        us4 o = {bf16r(v.x), bf16r(v.y), bf16r(v.z), bf16r(v.w)};
        *(us4*)(Tbf + i) = o;
        float s = v.x * v.x + v.y * v.y + v.z * v.z + v.w * v.w;
#pragma unroll
        for (int off = 8; off; off >>= 1) s += __shfl_xor(s, off);
        if ((tid & 15) == 0) sq_t[i >> 6] = s;
        return;
    }
    // transpose section: in [Rin][C] f32 -> out [C][Rin] bf16 (R = Rin)
    __shared__ float t[32][65];
    const float* in; ushort* out; int R, C;
    int lb = b - 4352;
    if (lb < 2048)      { in = i0; out = o0; R = 1024; C = 4096; }
    else if (lb < 2176) { in = i1; out = o1; R = 4096; C = 64;   lb -= 2048; }
    else if (lb < 2304) { in = i2; out = o2; R = 64;   C = 4096; lb -= 2176; }
    else                { in = i3; out = o3; R = 4096; C = 1024; lb -= 2304; }
    int bx = (lb % (C / 32)) * 32;   // in-col base
    int by = (lb / (C / 32)) * 64;   // in-row base
    int tx = tid & 31, ty = tid >> 5;   // ty 0..7
#pragma unroll
    for (int i = 0; i < 64; i += 8)
        t[tx][i + ty] = in[(size_t)(by + i + ty) * C + (bx + tx)];
    __syncthreads();
#pragma unroll
    for (int i = 0; i < 32; i += 8) {
        int c = i + ty;
        ushort2 o;
        o.x = bf16r(t[c][2 * tx]);
        o.y = bf16r(t[c][2 * tx + 1]);
        *(ushort2*)(&out[(size_t)(bx + c) * R + by + 2 * tx]) = o;
    }
}

// ---------------- MFMA GEMM (2-barrier structure, kept for GEMM3) ----------
// BM=128, BK=64, LDK=64, XOR swizzle k8^=row&7 on staging + read (0 bank
// conflicts).  BN=64: 4x1 waves of 32x64.
// EPI 0: +bias, gelu -> bf16 out.   EPI 1: +bias -> f32 out.
// EPI 2: raw fp32 partial (split-K): z==0 -> Out, z>0 -> Out2 if given.
template <int BN, int EPI, bool SWZ>
__global__ __launch_bounds__(256) void k_gemm(
        const ushort* __restrict__ A, const ushort* __restrict__ Bt,
        const float* __restrict__ bias, void* __restrict__ Out,
        float* __restrict__ Out2, int M, int N, int K, int KC) {
    constexpr int BM = 128, BK = 64;
    constexpr int WAVES_N = BN / 64;
    constexpr int WAVES_M = 4 / WAVES_N;
    constexpr int WM = BM / WAVES_M;
    constexpr int MT = WM / 16;
    constexpr int NT = 4;
    constexpr int CA = BM / 32, CB = BN / 32;

    __shared__ ushort sA[BM * 64];
    __shared__ ushort sB[BN * 64];

    const int tid  = threadIdx.x;
    const int wave = tid >> 6, lane = tid & 63;
    const int wm = wave / WAVES_N, wn = wave % WAVES_N;
    int bx = blockIdx.x, by = blockIdx.y;
    if constexpr (SWZ) {
        int lin = blockIdx.x + gridDim.x * blockIdx.y;
        by = lin % gridDim.y;          // m-tile fast => same XCD per A-row
        bx = lin / gridDim.y;
    }
    const int m0 = by * BM, n0 = bx * BN;
    const int lrow = lane & 15, lq = lane >> 4;
    const int srow8 = lane >> 3;
    const int sk8   = lane & 7;
    const int kbeg = blockIdx.z * KC;

    const ushort* pA[CA]; unsigned lA[CA];
#pragma unroll
    for (int j = 0; j < CA; ++j) {
        int c = wave * CA + j;
        int r = c * 8 + srow8;
        pA[j] = &A[(size_t)(m0 + r) * K + kbeg + ((sk8 ^ (r & 7)) * 8)];
        lA[j] = c * 512;
    }
    const ushort* pB[CB]; unsigned lB[CB];
#pragma unroll
    for (int j = 0; j < CB; ++j) {
        int c = wave * CB + j;
        int r = c * 8 + srow8;
        pB[j] = &Bt[(size_t)(n0 + r) * K + kbeg + ((sk8 ^ (r & 7)) * 8)];
        lB[j] = c * 512;
    }
    unsigned aoff[2][MT], boff[2][NT];
#pragma unroll
    for (int h = 0; h < 2; ++h) {
#pragma unroll
        for (int mt = 0; mt < MT; ++mt) {
            int r = wm * WM + mt * 16 + lrow;
            aoff[h][mt] = r * 64 + (((h * 4 + lq) ^ (r & 7)) * 8);
        }
#pragma unroll
        for (int nt = 0; nt < NT; ++nt) {
            int r = wn * 64 + nt * 16 + lrow;
            boff[h][nt] = r * 64 + (((h * 4 + lq) ^ (r & 7)) * 8);
        }
    }

    float4a acc[MT][NT];
#pragma unroll
    for (int mt = 0; mt < MT; ++mt)
#pragma unroll
        for (int nt = 0; nt < NT; ++nt)
            acc[mt][nt] = (float4a){0.f, 0.f, 0.f, 0.f};

    for (int k0 = 0; k0 < KC; k0 += BK) {
#pragma unroll
        for (int j = 0; j < CA; ++j) {
            gld_lds16(pA[j], &sA[lA[j]]);
            pA[j] += BK;
        }
#pragma unroll
        for (int j = 0; j < CB; ++j) {
            gld_lds16(pB[j], &sB[lB[j]]);
            pB[j] += BK;
        }
        __syncthreads();
#pragma unroll
        for (int h = 0; h < 2; ++h) {
            short8 af[MT], bfr[NT];
#pragma unroll
            for (int mt = 0; mt < MT; ++mt)
                af[mt] = *(short8*)(&sA[aoff[h][mt]]);
#pragma unroll
            for (int nt = 0; nt < NT; ++nt)
                bfr[nt] = *(short8*)(&sB[boff[h][nt]]);
#pragma unroll
            for (int mt = 0; mt < MT; ++mt)
#pragma unroll
                for (int nt = 0; nt < NT; ++nt)
                    acc[mt][nt] = __builtin_amdgcn_mfma_f32_16x16x32_bf16(
                        af[mt], bfr[nt], acc[mt][nt], 0, 0, 0);
        }
        __syncthreads();
    }

    float* dstp = nullptr;
    if constexpr (EPI == 2) {
        if (Out2 && blockIdx.z) dstp = Out2;
        else dstp = (float*)Out + (size_t)blockIdx.z * M * N;
    }
#pragma unroll
    for (int mt = 0; mt < MT; ++mt)
#pragma unroll
        for (int nt = 0; nt < NT; ++nt) {
            int col = n0 + wn * 64 + nt * 16 + lrow;
            float bv = 0.f;
            if constexpr (EPI != 2) bv = bias[col];
#pragma unroll
            for (int r = 0; r < 4; ++r) {
                int row = m0 + wm * WM + mt * 16 + lq * 4 + r;
                float v = acc[mt][nt][r] + bv;
                if constexpr (EPI == 0) {
                    ((ushort*)Out)[(size_t)row * N + col] = bf16r(fast_gelu(v));
                } else if constexpr (EPI == 1) {
                    ((float*)Out)[(size_t)row * N + col] = v;
                } else {
                    dstp[(size_t)row * N + col] = v;
                }
            }
        }
}

// ---------------- min-barrier 256-row GEMM (R4-proven, for GEMM4) ----------
// BM=256, BK=64, 512 threads = 8 waves, double-buffered LDS, XOR-slot
// swizzle.  ONE barrier per K-tile, counted waits, all issues front-loaded.
// R4/R7 verdict: mb = 41.4us for GEMM4, step-pipeline = 51.4us -> use mb.
template <int BN, int EPI, int CX, int CY>
__global__ __launch_bounds__(512, 2) void k_gemm256mb(
        const ushort* __restrict__ A, const ushort* __restrict__ Bt,
        const float* __restrict__ bias, void* __restrict__ Out,
        float* __restrict__ Out2, int M, int N, int K, int KC) {
    constexpr int BM = 256, BK = 64;
    constexpr int AI = 4;
    constexpr int BI = BN / 64;
    constexpr int WAVES_N = BN / 64;
    constexpr int WAVES_M = 8 / WAVES_N;
    constexpr int WM = BM / WAVES_M;
    constexpr int MT = WM / 16;
    constexpr int NT = 4;

    __shared__ ushort sA[2][BM * 64];
    __shared__ ushort sB[2][BN * 64];

    const int tid = threadIdx.x;
    const int wave = tid >> 6, lane = tid & 63;
    const int wm = wave / WAVES_N, wn = wave % WAVES_N;

    const int gx = gridDim.x, gy = gridDim.y;
    const int lin = blockIdx.x + gx * (blockIdx.y + gy * blockIdx.z);
    const int nwg = gx * gy * gridDim.z;
    const int cpx = nwg >> 3;
    const int swz = (lin & 7) * cpx + (lin >> 3);
    const int nz  = gx * gy;
    const int zz  = swz / nz;
    const int rr  = swz % nz;
    const int chunk = rr / (CX * CY);
    const int lcl   = rr % (CX * CY);
    const int ncx   = gx / CX;
    const int bx = (chunk % ncx) * CX + (lcl % CX);
    const int by = (chunk / ncx) * CY + (lcl / CX);

    const int m0 = by * BM, n0 = bx * BN;
    const int lrow = lane & 15, lq = lane >> 4;
    const int kbeg = zz * KC;
    const int nT = KC / BK;

    const int crow = tid >> 3;
    const int ck8  = (tid & 7) ^ (crow & 7);
    const ushort* pAbase = A  + (size_t)(m0 + crow) * K + kbeg + ck8 * 8;
    const ushort* pBbase = Bt + (size_t)(n0 + crow) * K + kbeg + ck8 * 8;

    const int a0  = (wm * WM + lrow) * 64;
    const int b0  = (wn * 64 + lrow) * 64;
    const int sw0 = ((lq) ^ (lrow & 7)) * 8;
    const int sw1 = ((4 + lq) ^ (lrow & 7)) * 8;

    float4a acc[MT][NT];
#pragma unroll
    for (int mt = 0; mt < MT; ++mt)
#pragma unroll
        for (int nt = 0; nt < NT; ++nt)
            acc[mt][nt] = (float4a){0.f, 0.f, 0.f, 0.f};

    // prologue: tile 0 -> buf 0
#pragma unroll
    for (int j = 0; j < AI; ++j)
        gld_lds16(pAbase + (size_t)j * 64 * K, &sA[0][j * 4096 + wave * 512]);
#pragma unroll
    for (int j = 0; j < BI; ++j)
        gld_lds16(pBbase + (size_t)j * 64 * K, &sB[0][j * 4096 + wave * 512]);
    wait_vmcnt<0>();
    __builtin_amdgcn_s_barrier();
    __builtin_amdgcn_sched_barrier(0);

    for (int t = 0; t < nT; ++t) {
        const int d = t & 1;
        const bool pf1 = (t + 1 < nT);
        const size_t koff1 = (size_t)(t + 1) * BK;

        short8 af0[MT], bfr0[NT], af1[MT], bfr1[NT];
#pragma unroll
        for (int mt = 0; mt < MT; ++mt)
            af0[mt] = *(const short8*)(&sA[d][a0 + mt * 1024 + sw0]);
#pragma unroll
        for (int nt = 0; nt < NT; ++nt)
            bfr0[nt] = *(const short8*)(&sB[d][b0 + nt * 1024 + sw0]);
        __builtin_amdgcn_sched_barrier(0);   // pin order: h0 batch first
#pragma unroll
        for (int mt = 0; mt < MT; ++mt)
            af1[mt] = *(const short8*)(&sA[d][a0 + mt * 1024 + sw1]);
#pragma unroll
        for (int nt = 0; nt < NT; ++nt)
            bfr1[nt] = *(const short8*)(&sB[d][b0 + nt * 1024 + sw1]);
        if (pf1) {                            // stage t+1 into dead buffer
#pragma unroll
            for (int j = 0; j < AI; ++j)
                gld_lds16(pAbase + (size_t)j * 64 * K + koff1,
                          &sA[d ^ 1][j * 4096 + wave * 512]);
#pragma unroll
            for (int j = 0; j < BI; ++j)
                gld_lds16(pBbase + (size_t)j * 64 * K + koff1,
                          &sB[d ^ 1][j * 4096 + wave * 512]);
        }
        wait_lgkmcnt<MT + 4>();               // af0+bfr0 complete
        __builtin_amdgcn_sched_barrier(0);
        __builtin_amdgcn_s_setprio(1);
#pragma unroll
        for (int mt = 0; mt < MT; ++mt)
#pragma unroll
            for (int nt = 0; nt < NT; ++nt)
                acc[mt][nt] = __builtin_amdgcn_mfma_f32_16x16x32_bf16(
                    af0[mt], bfr0[nt], acc[mt][nt], 0, 0, 0);
        __builtin_amdgcn_s_setprio(0);
        wait_lgkmcnt<0>();                    // af1+bfr1 complete
        __builtin_amdgcn_sched_barrier(0);
        __builtin_amdgcn_s_setprio(1);
#pragma unroll
        for (int mt = 0; mt < MT; ++mt)
#pragma unroll
            for (int nt = 0; nt < NT; ++nt)
                acc[mt][nt] = __builtin_amdgcn_mfma_f32_16x16x32_bf16(
                    af1[mt], bfr1[nt], acc[mt][nt], 0, 0, 0);
        __builtin_amdgcn_s_setprio(0);
        if (pf1) {                            // boundary: the only barrier
            wait_vmcnt<0>();
            __builtin_amdgcn_s_barrier();
            __builtin_amdgcn_sched_barrier(0);
        }
    }

    // epilogue
    float* dstp = nullptr;
    if constexpr (EPI == 2) {
        if (Out2 && zz) dstp = Out2;
        else dstp = (float*)Out + (size_t)zz * M * N;
    }
#pragma unroll
    for (int mt = 0; mt < MT; ++mt)
#pragma unroll
        for (int nt = 0; nt < NT; ++nt) {
            const int col = n0 + wn * 64 + nt * 16 + lrow;
            float bv = 0.f;
            if constexpr (EPI == 0) bv = bias[col];
#pragma unroll
            for (int r = 0; r < 4; ++r) {
                const int row = m0 + wm * WM + mt * 16 + lq * 4 + r;
                float v = acc[mt][nt][r] + bv;
                if constexpr (EPI == 0)
                    ((ushort*)Out)[(size_t)row * N + col] = bf16r(fast_gelu(v));
                else
                    dstp[(size_t)row * N + col] = v;
            }
        }
}

// ---------------- fused GEMM1+GEMM2: min-barrier 256x256 + latent partial --
// Main loop = mb<256>.  Epilogue: instead of writing enc-H (32MB) to HBM,
// write gelu(acc+b1) bf16 into the (dead) sA/sB LDS as sH[256][256] with the
// proven k-slot XOR swizzle, then mini-GEMM P[256x64] = sH x W2t-slice^T
// (contraction over this block's 256 DI cols) -> split-16 partial z = bx.
// W2t B-fragments read straight from global (512KB, L2-hot).  Eliminates
// 32MB H write + 32MB H read + the GEMM2 launch; ln64 reduces the same 16
// partials as before.
__global__ __launch_bounds__(512, 2) void k_gemm1f(
        const ushort* __restrict__ A, const ushort* __restrict__ Bt,
        const float* __restrict__ bias, const ushort* __restrict__ W2t,
        float* __restrict__ part, int M, int N, int K) {
    constexpr int BM = 256, BN = 256, BK = 64;
    constexpr int AI = 4, BI = 4;
    constexpr int WAVES_N = 4;
    constexpr int WM = 128;
    constexpr int MT = 8, NT = 4;
    constexpr int CX = 4, CY = 8;

    __shared__ ushort smem[65536];   // main: sA dbuf | sB dbuf ; epi: sH[256][256]

    const int tid = threadIdx.x;
    const int wave = tid >> 6, lane = tid & 63;
    const int wm = wave / WAVES_N, wn = wave % WAVES_N;

    // chunked XCD swizzle (grid 16x16, 256 blocks = 1/CU)
    const int gx = gridDim.x, gy = gridDim.y;
    const int lin = blockIdx.x + gx * blockIdx.y;
    const int cpx = (gx * gy) >> 3;
    const int swz = (lin & 7) * cpx + (lin >> 3);
    const int chunk = swz / (CX * CY);
    const int lcl   = swz % (CX * CY);
    const int ncx   = gx / CX;
    const int bx = (chunk % ncx) * CX + (lcl % CX);
    const int by = (chunk / ncx) * CY + (lcl / CX);

    const int m0 = by * BM, n0 = bx * BN;
    const int lrow = lane & 15, lq = lane >> 4;
    const int nT = K / BK;

    const int crow = tid >> 3;
    const int ck8  = (tid & 7) ^ (crow & 7);
    const ushort* pAbase = A  + (size_t)(m0 + crow) * K + ck8 * 8;
    const ushort* pBbase = Bt + (size_t)(n0 + crow) * K + ck8 * 8;

    const int a0  = (wm * WM + lrow) * 64;
    const int b0  = (wn * 64 + lrow) * 64;
    const int sw0 = ((lq) ^ (lrow & 7)) * 8;
    const int sw1 = ((4 + lq) ^ (lrow & 7)) * 8;

    float4a acc[MT][NT];
#pragma unroll
    for (int mt = 0; mt < MT; ++mt)
#pragma unroll
        for (int nt = 0; nt < NT; ++nt)
            acc[mt][nt] = (float4a){0.f, 0.f, 0.f, 0.f};

    // prologue: tile 0 -> buf 0
#pragma unroll
    for (int j = 0; j < AI; ++j)
        gld_lds16(pAbase + (size_t)j * 64 * K, &smem[j * 4096 + wave * 512]);
#pragma unroll
    for (int j = 0; j < BI; ++j)
        gld_lds16(pBbase + (size_t)j * 64 * K,
                  &smem[32768 + j * 4096 + wave * 512]);
    wait_vmcnt<0>();
    __builtin_amdgcn_s_barrier();
    __builtin_amdgcn_sched_barrier(0);

    for (int t = 0; t < nT; ++t) {
        const int d = t & 1;
        const bool pf1 = (t + 1 < nT);
        const size_t koff1 = (size_t)(t + 1) * BK;
        const ushort* sAd = &smem[d * 16384];
        const ushort* sBd = &smem[32768 + d * 16384];

        short8 af0[MT], bfr0[NT], af1[MT], bfr1[NT];
#pragma unroll
        for (int mt = 0; mt < MT; ++mt)
            af0[mt] = *(const short8*)(&sAd[a0 + mt * 1024 + sw0]);
#pragma unroll
        for (int nt = 0; nt < NT; ++nt)
            bfr0[nt] = *(const short8*)(&sBd[b0 + nt * 1024 + sw0]);
        __builtin_amdgcn_sched_barrier(0);
#pragma unroll
        for (int mt = 0; mt < MT; ++mt)
            af1[mt] = *(const short8*)(&sAd[a0 + mt * 1024 + sw1]);
#pragma unroll
        for (int nt = 0; nt < NT; ++nt)
            bfr1[nt] = *(const short8*)(&sBd[b0 + nt * 1024 + sw1]);
        if (pf1) {
#pragma unroll
            for (int j = 0; j < AI; ++j)
                gld_lds16(pAbase + (size_t)j * 64 * K + koff1,
                          &smem[(d ^ 1) * 16384 + j * 4096 + wave * 512]);
#pragma unroll
            for (int j = 0; j < BI; ++j)
                gld_lds16(pBbase + (size_t)j * 64 * K + koff1,
                          &smem[32768 + (d ^ 1) * 16384 + j * 4096 + wave * 512]);
        }
        wait_lgkmcnt<12>();                   // af0+bfr0 complete
        __builtin_amdgcn_sched_barrier(0);
        __builtin_amdgcn_s_setprio(1);
#pragma unroll
        for (int mt = 0; mt < MT; ++mt)
#pragma unroll
            for (int nt = 0; nt < NT; ++nt)
                acc[mt][nt] = __builtin_amdgcn_mfma_f32_16x16x32_bf16(
                    af0[mt], bfr0[nt], acc[mt][nt], 0, 0, 0);
        __builtin_amdgcn_s_setprio(0);
        wait_lgkmcnt<0>();
        __builtin_amdgcn_sched_barrier(0);
        __builtin_amdgcn_s_setprio(1);
#pragma unroll
        for (int mt = 0; mt < MT; ++mt)
#pragma unroll
            for (int nt = 0; nt < NT; ++nt)
                acc[mt][nt] = __builtin_amdgcn_mfma_f32_16x16x32_bf16(
                    af1[mt], bfr1[nt], acc[mt][nt], 0, 0, 0);
        __builtin_amdgcn_s_setprio(0);
        if (pf1) {
            wait_vmcnt<0>();
            __builtin_amdgcn_s_barrier();
            __builtin_amdgcn_sched_barrier(0);
        }
    }

    // ---- fused epilogue: gelu -> sH (LDS), then P = sH x W2slice^T --------
    __syncthreads();                          // all frag reads of smem done
#pragma unroll
    for (int mt = 0; mt < MT; ++mt)
#pragma unroll
        for (int nt = 0; nt < NT; ++nt) {
            const int c = wn * 64 + nt * 16 + lrow;     // local DI col 0..255
            const float bv = bias[n0 + c];
            const int s = c >> 3, cl = c & 7;
#pragma unroll
            for (int r_ = 0; r_ < 4; ++r_) {
                const int r = wm * WM + mt * 16 + lq * 4 + r_;
                const int sz = (s & 24) | ((s & 7) ^ (r & 7));
                smem[r * 256 + sz * 8 + cl] =
                    bf16r(fast_gelu(acc[mt][nt][r_] + bv));
            }
        }
    __syncthreads();                          // sH complete

    float4a pacc[2][4];
#pragma unroll
    for (int m2 = 0; m2 < 2; ++m2)
#pragma unroll
        for (int n2 = 0; n2 < 4; ++n2)
            pacc[m2][n2] = (float4a){0.f, 0.f, 0.f, 0.f};

    const ushort* gW2 = W2t + n0;             // W2t[64][4096], cols n0..n0+255
#pragma unroll
    for (int kk = 0; kk < 8; ++kk) {
        short8 af2[2], bf2[4];
#pragma unroll
        for (int m2 = 0; m2 < 2; ++m2) {
            const int r2 = wave * 32 + m2 * 16 + lrow;
            const int s2 = kk * 4 + lq;
            const int sz2 = (s2 & 24) | ((s2 & 7) ^ (r2 & 7));
            af2[m2] = *(const short8*)(&smem[r2 * 256 + sz2 * 8]);
        }
#pragma unroll
        for (int n2 = 0; n2 < 4; ++n2) {
            const int l = n2 * 16 + lrow;
            bf2[n2] = *(const short8*)(&gW2[(size_t)l * 4096 + kk * 32 + lq * 8]);
        }
#pragma unroll
        for (int m2 = 0; m2 < 2; ++m2)
#pragma unroll
            for (int n2 = 0; n2 < 4; ++n2)
                pacc[m2][n2] = __builtin_amdgcn_mfma_f32_16x16x32_bf16(
                    af2[m2], bf2[n2], pacc[m2][n2], 0, 0, 0);
    }

    float* pz = part + (size_t)bx * M * 64;   // split-16 partial z = bx
#pragma unroll
    for (int m2 = 0; m2 < 2; ++m2)
#pragma unroll
        for (int n2 = 0; n2 < 4; ++n2) {
            const int lat = n2 * 16 + lrow;
#pragma unroll
            for (int r_ = 0; r_ < 4; ++r_) {
                const int row = m0 + wave * 32 + m2 * 16 + lq * 4 + r_;
                pz[(size_t)row * 64 + lat] = pacc[m2][n2][r_];
            }
        }
}

// ---------------- fused MMD grams (separate-line accumulators) -------------
__global__ __launch_bounds__(256) void k_gram_all(
        const ushort* __restrict__ Tbf, const ushort* __restrict__ Lbf,
        const float* __restrict__ sq_t, const float* __restrict__ sq_l,
        float* __restrict__ accum) {
    __shared__ ushort sX[128 * 64];
    __shared__ ushort sY[128 * 64];
    __shared__ float red[4];

    int id = blockIdx.x;
    int pair, tbx, tby; float w;
    if (id < 1056) {
        pair = (id < 528) ? 0 : 1;
        int t = (pair == 0) ? id : id - 528;
        int r = (int)((sqrtf(8.0f * t + 1.0f) - 1.0f) * 0.5f);
        while ((r + 1) * (r + 2) / 2 <= t) ++r;
        while (r * (r + 1) / 2 > t) --r;
        tby = r; tbx = t - r * (r + 1) / 2;
        w = (tbx == tby) ? 1.0f : 2.0f;
    } else {
        pair = 2; int t = id - 1056;
        tbx = t & 31; tby = t >> 5; w = 1.0f;
    }
    const ushort* Xb = (pair == 1) ? Lbf : Tbf;
    const ushort* Yb = (pair == 0) ? Tbf : Lbf;
    const float* sqX = (pair == 1) ? sq_l : sq_t;
    const float* sqY = (pair == 0) ? sq_t : sq_l;

    const int tid  = threadIdx.x;
    const int wave = tid >> 6, lane = tid & 63;
    const int wm = wave >> 1, wn = wave & 1;
    const int bx = tbx * 128, by = tby * 128;
    const int lrow = lane & 15, lq = lane >> 4;
    const int srow8 = lane >> 3, sk8 = lane & 7;

#pragma unroll
    for (int j = 0; j < 4; ++j) {
        int c = wave * 4 + j;
        int r = c * 8 + srow8;
        int kc = (sk8 ^ (r & 7)) * 8;
        gld_lds16(&Xb[(size_t)(bx + r) * 64 + kc], &sX[c * 512]);
        gld_lds16(&Yb[(size_t)(by + r) * 64 + kc], &sY[c * 512]);
    }

    unsigned xoff[2][4], yoff[2][4];
#pragma unroll
    for (int h = 0; h < 2; ++h)
#pragma unroll
        for (int i = 0; i < 4; ++i) {
            int rx = wm * 64 + i * 16 + lrow;
            int ry = wn * 64 + i * 16 + lrow;
            xoff[h][i] = rx * 64 + (((h * 4 + lq) ^ (rx & 7)) * 8);
            yoff[h][i] = ry * 64 + (((h * 4 + lq) ^ (ry & 7)) * 8);
        }
    __syncthreads();

    float4a acc[4][4];
#pragma unroll
    for (int mt = 0; mt < 4; ++mt)
#pragma unroll
        for (int nt = 0; nt < 4; ++nt)
            acc[mt][nt] = (float4a){0.f, 0.f, 0.f, 0.f};

#pragma unroll
    for (int h = 0; h < 2; ++h) {
        short8 xf[4], yf[4];
#pragma unroll
        for (int mt = 0; mt < 4; ++mt)
            xf[mt] = *(short8*)(&sX[xoff[h][mt]]);
#pragma unroll
        for (int nt = 0; nt < 4; ++nt)
            yf[nt] = *(short8*)(&sY[yoff[h][nt]]);
#pragma unroll
        for (int mt = 0; mt < 4; ++mt)
#pragma unroll
            for (int nt = 0; nt < 4; ++nt)
                acc[mt][nt] = __builtin_amdgcn_mfma_f32_16x16x32_bf16(
                    xf[mt], yf[nt], acc[mt][nt], 0, 0, 0);
    }

    float sy[4];
#pragma unroll
    for (int nt = 0; nt < 4; ++nt)
        sy[nt] = sqY[by + wn * 64 + nt * 16 + lrow];
    float s = 0.f;
#pragma unroll
    for (int mt = 0; mt < 4; ++mt)
#pragma unroll
        for (int r = 0; r < 4; ++r) {
            float sx = sqX[bx + wm * 64 + mt * 16 + lq * 4 + r];
#pragma unroll
            for (int nt = 0; nt < 4; ++nt)
                s += __expf((2.0f * acc[mt][nt][r] - sx - sy[nt]) * (1.0f / 4096.0f));
        }
    s *= w;
#pragma unroll
    for (int off = 32; off; off >>= 1) s += __shfl_xor(s, off);
    if ((tid & 63) == 0) red[tid >> 6] = s;
    __syncthreads();
    if (tid == 0) atomicAdd(accum + pair * 8, red[0] + red[1] + red[2] + red[3]);
}

// ---------------- LayerNorm over 64, split-K reduce, + latent sqnorm -------
__global__ __launch_bounds__(256) void k_ln64_red(
        const float* __restrict__ part, int npart,
        const float* __restrict__ bias, const float* __restrict__ g,
        const float* __restrict__ b, float* __restrict__ outf,
        ushort* __restrict__ outb, float* __restrict__ sq_l) {
    int wave = threadIdx.x >> 6, lane = threadIdx.x & 63;
    int row = blockIdx.x * 4 + wave;
    float x = bias[lane];
    for (int s = 0; s < npart; ++s)
        x += part[(size_t)s * 4096 * 64 + row * 64 + lane];
    float s = x;
#pragma unroll
    for (int off = 32; off; off >>= 1) s += __shfl_xor(s, off);
    float mu = s * (1.0f / 64.0f);
    float d = x - mu;
    float v = d * d;
#pragma unroll
    for (int off = 32; off; off >>= 1) v += __shfl_xor(v, off);
    float rs = rsqrtf(v * (1.0f / 64.0f) + 1e-9f);
    float y = d * rs * g[lane] + b[lane];
    outf[row * 64 + lane] = y;
    outb[row * 64 + lane] = bf16r(y);
    float q = y * y;
#pragma unroll
    for (int off = 32; off; off >>= 1) q += __shfl_xor(q, off);
    if (lane == 0) sq_l[row] = q;
}

// ---------------- LayerNorm over 1024 with 2-partial reduce ----------------
// p1 may alias out (read-before-write within the same block/row).
__global__ __launch_bounds__(256) void k_ln1024_red(
        const float* __restrict__ p0, const float* __restrict__ p1,
        const float* __restrict__ bias, const float* __restrict__ g,
        const float* __restrict__ b, float* __restrict__ out) {
    __shared__ float red[4];
    int row = blockIdx.x, tid = threadIdx.x;
    const float4 v0 = *(const float4*)(p0 + (size_t)row * 1024 + tid * 4);
    const float4 v1 = *(const float4*)(p1 + (size_t)row * 1024 + tid * 4);
    const float4 bb = *(const float4*)(bias + tid * 4);
    float4 v;
    v.x = v0.x + v1.x + bb.x;
    v.y = v0.y + v1.y + bb.y;
    v.z = v0.z + v1.z + bb.z;
    v.w = v0.w + v1.w + bb.w;
    float s = v.x + v.y + v.z + v.w;
#pragma unroll
    for (int off = 32; off; off >>= 1) s += __shfl_xor(s, off);
    if ((tid & 63) == 0) red[tid >> 6] = s;
    __syncthreads();
    float mu = (red[0] + red[1] + red[2] + red[3]) * (1.0f / 1024.0f);
    float dx = v.x - mu, dy = v.y - mu, dz = v.z - mu, dw = v.w - mu;
    float q = dx * dx + dy * dy + dz * dz + dw * dw;
#pragma unroll
    for (int off = 32; off; off >>= 1) q += __shfl_xor(q, off);
    __syncthreads();
    if ((tid & 63) == 0) red[tid >> 6] = q;
    __syncthreads();
    float rs = rsqrtf((red[0] + red[1] + red[2] + red[3]) * (1.0f / 1024.0f) + 1e-9f);
    const float4 gv = *(const float4*)(g + tid * 4);
    const float4 bv = *(const float4*)(b + tid * 4);
    float4 o;
    o.x = dx * rs * gv.x + bv.x;
    o.y = dy * rs * gv.y + bv.y;
    o.z = dz * rs * gv.z + bv.z;
    o.w = dw * rs * gv.w + bv.w;
    *(float4*)(out + (size_t)row * 1024 + tid * 4) = o;
}

__global__ void k_finalize(const float* __restrict__ accum, float* __restrict__ out) {
    // km_i = accum_i / 4096^2 ; reg = (km0 + km1 - 2*km2) / B * S = mmd * 64
    out[0] = (accum[0] + accum[8] - 2.0f * accum[16]) * (64.0f / (4096.0f * 4096.0f));
}

// ---------------------------------------------------------------------------
extern "C" void kernel_launch(void* const* d_in, const int* in_sizes, int n_in,
                              void* d_out, int out_size, void* d_ws, size_t ws_size,
                              hipStream_t stream) {
    const float* hidden   = (const float*)d_in[0];
    const float* tsamp    = (const float*)d_in[1];
    const float* enc_w1   = (const float*)d_in[2];
    const float* enc_b1   = (const float*)d_in[3];
    const float* enc_w2   = (const float*)d_in[4];
    const float* enc_b2   = (const float*)d_in[5];
    const float* enc_ln_g = (const float*)d_in[6];
    const float* enc_ln_b = (const float*)d_in[7];
    const float* dec_w1   = (const float*)d_in[8];
    const float* dec_b1   = (const float*)d_in[9];
    const float* dec_w2   = (const float*)d_in[10];
    const float* dec_b2   = (const float*)d_in[11];
    const float* dec_ln_g = (const float*)d_in[12];
    const float* dec_ln_b = (const float*)d_in[13];

    float* out      = (float*)d_out;
    float* recon    = out;                 // 4096*1024
    float* latent_f = out + 4194304;       // 4096*64
    float* reg      = out + 4456448;       // scalar

    char* ws = (char*)d_ws;
    const size_t MB = 1024 * 1024;
    ushort* A1bf = (ushort*)(ws + 0);                 // 8MB  hidden bf16 (dead after GEMM1)
    ushort* W1t  = (ushort*)(ws + 8 * MB);            // 8MB  (dead after GEMM1)
    float*  h4p0 = (float*)(ws + 0);                  // 16MB GEMM4 partial z=0 (z=1 -> recon buf)
    ushort* H1bf = (ushort*)(ws + 16 * MB);           // 32MB dec hidden (GEMM3 out)
    float*  part = (float*)(ws + 16 * MB);            // 16MB enc split-16 partials
                                                      //      (in H1bf region; ln64 drains it
                                                      //       before GEMM3 overwrites)
    ushort* W4t  = (ushort*)(ws + 48 * MB);           // 8MB  [1024,4096]
    ushort* W2t  = (ushort*)(ws + 56 * MB);           // 512K [64,4096]
    ushort* W3t  = (ushort*)(ws + 56 * MB + 512 * 1024); // 512K [4096,64]
    ushort* Lbf  = (ushort*)(ws + 57 * MB);           // 512K latent bf16
    float*  sq_t = (float*)(ws + 59 * MB);            // 16KB
    float*  sq_l = (float*)(ws + 59 * MB + 16384);    // 16KB
    float*  acc3 = (float*)(ws + 59 * MB + 32768);    // 3 accumulators @ 64B stride
    ushort* Tbf  = (ushort*)(ws + 59 * MB + 65536);   // 512K tsamp bf16

    // pre-pass: conversions, transposes (64x32 ushort2 tiles), sqnorms, zeroing
    k_pre<<<8704, 256, 0, stream>>>(hidden, A1bf, tsamp, Tbf, sq_t, acc3,
                                    enc_w1, W1t, enc_w2, W2t,
                                    dec_w1, W3t, dec_w2, W4t);

    // encoder: fused GEMM1+GEMM2 (256x256 mb + latent-partial epilogue)
    k_gemm1f<<<dim3(16, 16, 1), 512, 0, stream>>>(
        A1bf, W1t, enc_b1, W2t, part, 4096, 4096, 1024);
    k_ln64_red<<<1024, 256, 0, stream>>>(part, 16, enc_b2, enc_ln_g, enc_ln_b,
                                         latent_f, Lbf, sq_l);

    // decoder: GEMM3 K=64 (write-bound, old structure)
    k_gemm<64, 0, false><<<dim3(64, 32, 1), 256, 0, stream>>>(
        Lbf, W3t, dec_b1, H1bf, nullptr, 4096, 4096, 64, 64);
    // GEMM4: min-barrier 256x128 (R4-proven 41.4us), split-K=2 -> 256 blocks
    k_gemm256mb<128, 2, 8, 4><<<dim3(8, 16, 2), 512, 0, stream>>>(
        H1bf, W4t, nullptr, h4p0, recon, 4096, 1024, 4096, 2048);
    k_ln1024_red<<<4096, 256, 0, stream>>>(h4p0, recon, dec_b2, dec_ln_g,
                                           dec_ln_b, recon);

    // MMD: grams (separate-line accumulators), then tiny finalize
    k_gram_all<<<2080, 256, 0, stream>>>(Tbf, Lbf, sq_t, sq_l, acc3);
    k_finalize<<<1, 1, 0, stream>>>(acc3, reg);
}